// Round 2
// 1606.209 us; speedup vs baseline: 1.1106x; 1.1106x over previous
//
#include <hip/hip_runtime.h>
#include <hip/hip_bf16.h>
#include <math.h>

#define T_    2048
#define HID_  1024
#define NH_   16
#define NKV_  4
#define HD_   64
#define E_    8
#define TOPK_ 2
#define INTER_ 3584
#define EPS_  1e-6f

typedef __attribute__((ext_vector_type(8))) short short8;
typedef __attribute__((ext_vector_type(4))) float floatx4;

__device__ inline short f2bf(float f) {
    __hip_bfloat16 b = __float2bfloat16(f);
    return *reinterpret_cast<short*>(&b);
}

__device__ inline void cvt_store16(short* dst, float4 a, float4 b, float4 c, float4 d) {
    short8 lo, hi;
    lo[0] = f2bf(a.x); lo[1] = f2bf(a.y); lo[2] = f2bf(a.z); lo[3] = f2bf(a.w);
    lo[4] = f2bf(b.x); lo[5] = f2bf(b.y); lo[6] = f2bf(b.z); lo[7] = f2bf(b.w);
    hi[0] = f2bf(c.x); hi[1] = f2bf(c.y); hi[2] = f2bf(c.z); hi[3] = f2bf(c.w);
    hi[4] = f2bf(d.x); hi[5] = f2bf(d.y); hi[6] = f2bf(d.z); hi[7] = f2bf(d.w);
    *(short8*)dst = lo;
    *(short8*)(dst + 8) = hi;
}

// async global->LDS, 16B per lane. LDS dest must be wave-uniform-base + lane*16.
__device__ inline void async_copy16(short* lds, const short* g) {
    __builtin_amdgcn_global_load_lds((const __attribute__((address_space(1))) void*)g,
                                     (__attribute__((address_space(3))) void*)lds, 16, 0, 0);
}

// ---------------- RMSNorm: one block (256 thr) per row ----------------
__global__ __launch_bounds__(256) void rmsnorm_kernel(const float* __restrict__ x,
                                                      const float* __restrict__ w,
                                                      float* __restrict__ o) {
    int t = blockIdx.x;
    const float* xr = x + (size_t)t * HID_;
    float s = 0.f;
    for (int d = threadIdx.x; d < HID_; d += 256) { float v = xr[d]; s += v * v; }
    __shared__ float red[256];
    red[threadIdx.x] = s; __syncthreads();
    for (int off = 128; off > 0; off >>= 1) {
        if (threadIdx.x < off) red[threadIdx.x] += red[threadIdx.x + off];
        __syncthreads();
    }
    float inv = rsqrtf(red[0] / (float)HID_ + EPS_);
    for (int d = threadIdx.x; d < HID_; d += 256)
        o[(size_t)t * HID_ + d] = w[d] * xr[d] * inv;
}

// ---------------- Generic fp32 GEMM: C[M,N] = A[M,K] @ B[N,K]^T (+add) ----------------
__global__ __launch_bounds__(256) void gemm_f32(const float* __restrict__ A,
                                                const float* __restrict__ B,
                                                float* __restrict__ C,
                                                const float* __restrict__ addsrc,
                                                int M, int N, int K) {
    __shared__ float As[16][65];
    __shared__ float Bs[16][65];
    int tid = threadIdx.x;
    int tx = tid & 15, ty = tid >> 4;
    int bm = blockIdx.y * 64, bn = blockIdx.x * 64;
    float acc[4][4];
#pragma unroll
    for (int i = 0; i < 4; i++)
#pragma unroll
        for (int j = 0; j < 4; j++) acc[i][j] = 0.f;

    int mL[4], kL[4];
#pragma unroll
    for (int l = 0; l < 4; l++) { int idx = tid + l * 256; mL[l] = idx >> 4; kL[l] = idx & 15; }

    for (int k0 = 0; k0 < K; k0 += 16) {
#pragma unroll
        for (int l = 0; l < 4; l++) {
            int m = mL[l], kk = kL[l];
            int gr = bm + m;
            As[kk][m] = (gr < M) ? A[(size_t)gr * K + k0 + kk] : 0.f;
            int gc = bn + m;
            Bs[kk][m] = (gc < N) ? B[(size_t)gc * K + k0 + kk] : 0.f;
        }
        __syncthreads();
#pragma unroll
        for (int kk = 0; kk < 16; kk++) {
            float a[4], b[4];
#pragma unroll
            for (int i = 0; i < 4; i++) a[i] = As[kk][ty * 4 + i];
#pragma unroll
            for (int j = 0; j < 4; j++) b[j] = Bs[kk][tx * 4 + j];
#pragma unroll
            for (int i = 0; i < 4; i++)
#pragma unroll
                for (int j = 0; j < 4; j++) acc[i][j] += a[i] * b[j];
        }
        __syncthreads();
    }
#pragma unroll
    for (int i = 0; i < 4; i++) {
        int r = bm + ty * 4 + i;
        if (r >= M) continue;
#pragma unroll
        for (int j = 0; j < 4; j++) {
            int c = bn + tx * 4 + j;
            if (c >= N) continue;
            float v = acc[i][j];
            if (addsrc) v += addsrc[(size_t)r * N + c];
            C[(size_t)r * N + c] = v;
        }
    }
}

// ---------------- RoPE in-place on q and k ----------------
__global__ void rope_kernel(float* __restrict__ qb, float* __restrict__ kb,
                            const int* __restrict__ pos_ids) {
    int idx = blockIdx.x * blockDim.x + threadIdx.x;
    const int totq = T_ * NH_ * 32;
    const int totk = T_ * NKV_ * 32;
    if (idx >= totq + totk) return;
    float* buf; int t, hh, i, hw;
    if (idx < totq) { buf = qb; hw = NH_;  t = idx / (NH_ * 32); int r = idx % (NH_ * 32); hh = r / 32; i = r % 32; }
    else { idx -= totq; buf = kb; hw = NKV_; t = idx / (NKV_ * 32); int r = idx % (NKV_ * 32); hh = r / 32; i = r % 32; }
    float pos = (float)pos_ids[t];
    float inv = expf(-(float)i * (13.815510558f / 32.0f));
    float fr = pos * inv;
    float c = cosf(fr), s = sinf(fr);
    size_t base = (size_t)t * hw * 64 + (size_t)hh * 64;
    float x1 = buf[base + i], x2 = buf[base + i + 32];
    buf[base + i]      = x1 * c - x2 * s;
    buf[base + i + 32] = x2 * c + x1 * s;
}

// ---------------- Flash attention: one block per (head, 64-row q-tile) ----------------
__global__ __launch_bounds__(256) void flash_attn_kernel(const float* __restrict__ qb,
                                                         const float* __restrict__ kb,
                                                         const float* __restrict__ vb,
                                                         float* __restrict__ ob) {
    __shared__ float Qs[64][68];
    __shared__ float Ks[64][68];
    __shared__ float Vs[64][68];
    __shared__ float Ps[64][68];

    int bid = blockIdx.x;
    int h = bid & 15;
    int qr = bid >> 4;
    int qt = (qr & 1) ? (31 - (qr >> 1)) : (qr >> 1);
    int q0 = qt * 64;
    int kvh = h >> 2;
    int tid = threadIdx.x;
    int tx = tid & 15, ty = tid >> 4;

#pragma unroll
    for (int l = 0; l < 16; l++) {
        int idx = l * 256 + tid;
        int m = idx >> 6, d = idx & 63;
        Qs[d][m] = qb[(size_t)(q0 + m) * (NH_ * HD_) + h * HD_ + d];
    }

    float o_acc[4][4];
    float m_i[4], l_i[4];
#pragma unroll
    for (int i = 0; i < 4; i++) {
        m_i[i] = -INFINITY; l_i[i] = 0.f;
#pragma unroll
        for (int j = 0; j < 4; j++) o_acc[i][j] = 0.f;
    }

    for (int t0 = 0; t0 <= q0; t0 += 64) {
        __syncthreads();
#pragma unroll
        for (int l = 0; l < 16; l++) {
            int idx = l * 256 + tid;
            int m = idx >> 6, d = idx & 63;
            size_t g = (size_t)(t0 + m) * (NKV_ * HD_) + kvh * HD_ + d;
            Ks[d][m] = kb[g];
            Vs[m][d] = vb[g];
        }
        __syncthreads();

        float s[4][4];
#pragma unroll
        for (int i = 0; i < 4; i++)
#pragma unroll
            for (int j = 0; j < 4; j++) s[i][j] = 0.f;
#pragma unroll 4
        for (int kk = 0; kk < 64; kk++) {
            float4 a4 = *(const float4*)&Qs[kk][ty * 4];
            float4 b4 = *(const float4*)&Ks[kk][tx * 4];
            float a[4] = {a4.x, a4.y, a4.z, a4.w};
            float b[4] = {b4.x, b4.y, b4.z, b4.w};
#pragma unroll
            for (int i = 0; i < 4; i++)
#pragma unroll
                for (int j = 0; j < 4; j++) s[i][j] += a[i] * b[j];
        }

        bool diag = (t0 == q0);
#pragma unroll
        for (int i = 0; i < 4; i++) {
#pragma unroll
            for (int j = 0; j < 4; j++) {
                s[i][j] *= 0.125f;
                if (diag && (t0 + tx * 4 + j > q0 + ty * 4 + i)) s[i][j] = -INFINITY;
            }
        }

#pragma unroll
        for (int i = 0; i < 4; i++) {
            float mx = fmaxf(fmaxf(s[i][0], s[i][1]), fmaxf(s[i][2], s[i][3]));
#pragma unroll
            for (int off = 8; off >= 1; off >>= 1) mx = fmaxf(mx, __shfl_xor(mx, off));
            float mn = fmaxf(m_i[i], mx);
            float alpha = __expf(m_i[i] - mn);
            float rs = 0.f;
#pragma unroll
            for (int j = 0; j < 4; j++) { float p = __expf(s[i][j] - mn); s[i][j] = p; rs += p; }
#pragma unroll
            for (int off = 8; off >= 1; off >>= 1) rs += __shfl_xor(rs, off);
            l_i[i] = l_i[i] * alpha + rs;
            m_i[i] = mn;
#pragma unroll
            for (int j = 0; j < 4; j++) o_acc[i][j] *= alpha;
        }

#pragma unroll
        for (int j = 0; j < 4; j++)
#pragma unroll
            for (int i = 0; i < 4; i++)
                Ps[tx * 4 + j][ty * 4 + i] = s[i][j];
        __syncthreads();

#pragma unroll 4
        for (int kk = 0; kk < 64; kk++) {
            float4 a4 = *(const float4*)&Ps[kk][ty * 4];
            float4 b4 = *(const float4*)&Vs[kk][tx * 4];
            float a[4] = {a4.x, a4.y, a4.z, a4.w};
            float b[4] = {b4.x, b4.y, b4.z, b4.w};
#pragma unroll
            for (int i = 0; i < 4; i++)
#pragma unroll
                for (int j = 0; j < 4; j++) o_acc[i][j] += a[i] * b[j];
        }
    }

#pragma unroll
    for (int i = 0; i < 4; i++) {
        float invl = 1.f / l_i[i];
        int r = q0 + ty * 4 + i;
#pragma unroll
        for (int j = 0; j < 4; j++)
            ob[(size_t)r * (NH_ * HD_) + h * HD_ + tx * 4 + j] = o_acc[i][j] * invl;
    }
}

// ---------------- Gating: one wave per token ----------------
__global__ __launch_bounds__(64) void gating_kernel(const float* __restrict__ xn2,
                                                    const float* __restrict__ gate_w,
                                                    int* __restrict__ sel,
                                                    float* __restrict__ wt,
                                                    int* __restrict__ counts) {
    int t = blockIdx.x, lane = threadIdx.x;
    const float* x = xn2 + (size_t)t * HID_;
    float logits[E_];
    for (int e = 0; e < E_; e++) {
        float p = 0.f;
        for (int d = lane; d < HID_; d += 64) p += x[d] * gate_w[(size_t)e * HID_ + d];
#pragma unroll
        for (int off = 32; off > 0; off >>= 1) p += __shfl_xor(p, off);
        logits[e] = p;
    }
    float mx = logits[0];
    for (int e = 1; e < E_; e++) mx = fmaxf(mx, logits[e]);
    float pr[E_]; float sum = 0.f;
    for (int e = 0; e < E_; e++) { pr[e] = __expf(logits[e] - mx); sum += pr[e]; }
    int e1 = 0; float p1 = pr[0];
    for (int e = 1; e < E_; e++) if (pr[e] > p1) { p1 = pr[e]; e1 = e; }
    int e2 = -1; float p2 = -1.f;
    for (int e = 0; e < E_; e++) if (e != e1 && pr[e] > p2) { p2 = pr[e]; e2 = e; }
    if (lane == 0) {
        float denom = p1 + p2;
        sel[t * 2] = e1; sel[t * 2 + 1] = e2;
        wt[t * 2] = p1 / denom; wt[t * 2 + 1] = p2 / denom;
        atomicAdd(&counts[e1], 1);
        atomicAdd(&counts[e2], 1);
    }
}

__global__ void init_counts_kernel(int* counts) {
    if (threadIdx.x < E_) counts[threadIdx.x] = 0;
}

__global__ void prefix_kernel(const int* __restrict__ counts, int* __restrict__ ebase,
                              int* __restrict__ cursor) {
    if (threadIdx.x == 0) {
        int b = 0;
        for (int e = 0; e < E_; e++) { ebase[e] = b; cursor[e] = b; b += counts[e]; }
    }
}

__global__ void scatter_kernel(const int* __restrict__ sel, const float* __restrict__ wt,
                               int* __restrict__ cursor, int* __restrict__ tok_list,
                               float* __restrict__ wt_list) {
    int t = blockIdx.x * blockDim.x + threadIdx.x;
    if (t >= T_) return;
    for (int j = 0; j < 2; j++) {
        int e = sel[t * 2 + j];
        float w = wt[t * 2 + j];
        int p = atomicAdd(&cursor[e], 1);
        tok_list[p] = t;
        wt_list[p] = w;
    }
}

// ---------------- fp32 -> bf16 bulk convert (RNE, memory-bound) ----------------
__global__ __launch_bounds__(256) void cvt_bf16_kernel(const float* __restrict__ src,
                                                       short* __restrict__ dst, int n8) {
    int stride = gridDim.x * blockDim.x;
    for (int i = blockIdx.x * blockDim.x + threadIdx.x; i < n8; i += stride) {
        float4 a = ((const float4*)src)[2 * i];
        float4 b = ((const float4*)src)[2 * i + 1];
        short8 o;
        o[0] = f2bf(a.x); o[1] = f2bf(a.y); o[2] = f2bf(a.z); o[3] = f2bf(a.w);
        o[4] = f2bf(b.x); o[5] = f2bf(b.y); o[6] = f2bf(b.z); o[7] = f2bf(b.w);
        ((short8*)dst)[i] = o;
    }
}

// ---------------- MoE GEMM 1&3 v2: bf16 inputs, global_load_lds, 2-phase pipeline ----------------
// 128x128 tile, BK=32, 4 waves of 4x4 mfma_f32_16x16x32_bf16.
// LDS linear [128][32] bf16 per matrix (required by global_load_lds), double-buffered.
// Per K-step: issue next tile's 6 async 16B copies/thread, then ds_read+MFMA current,
// then ONE __syncthreads() (drains vmcnt -> next buffer ready, lgkm -> cur buffer free).
__global__ __launch_bounds__(256, 2) void moe_gemm13_v2(const short* __restrict__ Xb,
                                                        const short* __restrict__ w1b,
                                                        const short* __restrict__ w3b,
                                                        const int* __restrict__ tok_list,
                                                        const int* __restrict__ ebase,
                                                        const int* __restrict__ counts,
                                                        __hip_bfloat16* __restrict__ h13b) {
    int e = blockIdx.z;
    int cnt = counts[e];
    int bm = blockIdx.y * 128;
    if (cnt <= 0 || bm >= cnt) return;
    int base = ebase[e];
    int bn = blockIdx.x * 128;

    __shared__ alignas(16) short lds[2][3][128 * 32];  // 48 KiB

    int tid = threadIdx.x;
    int sr = tid >> 2;            // staging row 0..63 (and +64 for second segment)
    int sc = (tid & 3) * 8;       // staging col (elements)
    int ldst = tid * 8;           // LDS element offset = sr*32 + sc (linear); +2048 -> row sr+64

    int lr0 = bm + sr, lr1 = bm + sr + 64;
    int tok0 = tok_list[base + (lr0 < cnt ? lr0 : cnt - 1)];
    int tok1 = tok_list[base + (lr1 < cnt ? lr1 : cnt - 1)];
    const short* aG0 = Xb + (size_t)tok0 * HID_ + sc;
    const short* aG1 = Xb + (size_t)tok1 * HID_ + sc;
    const short* b1G0 = w1b + (size_t)e * INTER_ * HID_ + (size_t)(bn + sr) * HID_ + sc;
    const short* b1G1 = b1G0 + (size_t)64 * HID_;
    const short* b3G0 = w3b + (size_t)e * INTER_ * HID_ + (size_t)(bn + sr) * HID_ + sc;
    const short* b3G1 = b3G0 + (size_t)64 * HID_;

    int wvid = tid >> 6, lane = tid & 63;
    int wm = (wvid >> 1) * 64, wn = (wvid & 1) * 64;
    int l15 = lane & 15, quad = lane >> 4;

    floatx4 acc1[4][4], acc3[4][4];
#pragma unroll
    for (int i = 0; i < 4; i++)
#pragma unroll
        for (int j = 0; j < 4; j++) { acc1[i][j] = (floatx4)0.f; acc3[i][j] = (floatx4)0.f; }

#define STAGE13(b, k0) do {                                          \
        async_copy16(&lds[b][0][ldst],        aG0 + (k0));           \
        async_copy16(&lds[b][0][ldst + 2048], aG1 + (k0));           \
        async_copy16(&lds[b][1][ldst],        b1G0 + (k0));          \
        async_copy16(&lds[b][1][ldst + 2048], b1G1 + (k0));          \
        async_copy16(&lds[b][2][ldst],        b3G0 + (k0));          \
        async_copy16(&lds[b][2][ldst + 2048], b3G1 + (k0));          \
    } while (0)

    STAGE13(0, 0);
    __syncthreads();   // drain prologue

    int cur = 0;
    for (int k0 = 0; k0 < HID_; k0 += 32) {
        if (k0 + 32 < HID_) STAGE13(cur ^ 1, k0 + 32);   // in flight during compute

        const short* XaR = &lds[cur][0][(wm + l15) * 32 + quad * 8];
        const short* W1r = &lds[cur][1][(wn + l15) * 32 + quad * 8];
        const short* W3r = &lds[cur][2][(wn + l15) * 32 + quad * 8];
        short8 af[4], b1f[4], b3f[4];
#pragma unroll
        for (int i = 0; i < 4; i++) af[i] = *(const short8*)(XaR + i * 16 * 32);
#pragma unroll
        for (int j = 0; j < 4; j++) {
            b1f[j] = *(const short8*)(W1r + j * 16 * 32);
            b3f[j] = *(const short8*)(W3r + j * 16 * 32);
        }
#pragma unroll
        for (int i = 0; i < 4; i++)
#pragma unroll
            for (int j = 0; j < 4; j++) {
                acc1[i][j] = __builtin_amdgcn_mfma_f32_16x16x32_bf16(af[i], b1f[j], acc1[i][j], 0, 0, 0);
                acc3[i][j] = __builtin_amdgcn_mfma_f32_16x16x32_bf16(af[i], b3f[j], acc3[i][j], 0, 0, 0);
            }
        __syncthreads();   // vmcnt(0): next buf staged; lgkmcnt: cur buf free
        cur ^= 1;
    }
#undef STAGE13

    // epilogue: C layout col=lane&15, row=quad*4+reg
#pragma unroll
    for (int i = 0; i < 4; i++) {
#pragma unroll
        for (int reg = 0; reg < 4; reg++) {
            int lrow = bm + wm + i * 16 + quad * 4 + reg;
            if (lrow >= cnt) continue;
            size_t rowoff = (size_t)(base + lrow) * INTER_;
#pragma unroll
            for (int j = 0; j < 4; j++) {
                float a = acc1[i][j][reg];
                float v = (a / (1.f + __expf(-a))) * acc3[i][j][reg];
                h13b[rowoff + bn + wn + j * 16 + l15] = __float2bfloat16(v);
            }
        }
    }
}

// ---------------- MoE GEMM 2 v2: out[tok] += wt * (h13b @ w2b^T), same pipeline ----------------
__global__ __launch_bounds__(256, 2) void moe_gemm2_v2(const short* __restrict__ h13s,
                                                       const short* __restrict__ w2b,
                                                       const int* __restrict__ tok_list,
                                                       const float* __restrict__ wt_list,
                                                       const int* __restrict__ ebase,
                                                       const int* __restrict__ counts,
                                                       float* __restrict__ out) {
    int e = blockIdx.z;
    int cnt = counts[e];
    int bm = blockIdx.y * 128;
    if (cnt <= 0 || bm >= cnt) return;
    int base = ebase[e];
    int bn = blockIdx.x * 128;

    __shared__ alignas(16) short lds[2][2][128 * 32];  // 32 KiB

    int tid = threadIdx.x;
    int sr = tid >> 2;
    int sc = (tid & 3) * 8;
    int ldst = tid * 8;

    int lr0 = bm + sr, lr1 = bm + sr + 64;
    int slot0 = base + (lr0 < cnt ? lr0 : cnt - 1);
    int slot1 = base + (lr1 < cnt ? lr1 : cnt - 1);
    const short* aG0 = h13s + (size_t)slot0 * INTER_ + sc;
    const short* aG1 = h13s + (size_t)slot1 * INTER_ + sc;
    const short* bG0 = w2b + (size_t)e * HID_ * INTER_ + (size_t)(bn + sr) * INTER_ + sc;
    const short* bG1 = bG0 + (size_t)64 * INTER_;

    int wvid = tid >> 6, lane = tid & 63;
    int wm = (wvid >> 1) * 64, wn = (wvid & 1) * 64;
    int l15 = lane & 15, quad = lane >> 4;

    floatx4 acc[4][4];
#pragma unroll
    for (int i = 0; i < 4; i++)
#pragma unroll
        for (int j = 0; j < 4; j++) acc[i][j] = (floatx4)0.f;

#define STAGE2(b, k0) do {                                          \
        async_copy16(&lds[b][0][ldst],        aG0 + (k0));          \
        async_copy16(&lds[b][0][ldst + 2048], aG1 + (k0));          \
        async_copy16(&lds[b][1][ldst],        bG0 + (k0));          \
        async_copy16(&lds[b][1][ldst + 2048], bG1 + (k0));          \
    } while (0)

    STAGE2(0, 0);
    __syncthreads();

    int cur = 0;
    for (int k0 = 0; k0 < INTER_; k0 += 32) {
        if (k0 + 32 < INTER_) STAGE2(cur ^ 1, k0 + 32);

        const short* XaR = &lds[cur][0][(wm + l15) * 32 + quad * 8];
        const short* WsR = &lds[cur][1][(wn + l15) * 32 + quad * 8];
        short8 af[4], bf_[4];
#pragma unroll
        for (int i = 0; i < 4; i++) af[i] = *(const short8*)(XaR + i * 16 * 32);
#pragma unroll
        for (int j = 0; j < 4; j++) bf_[j] = *(const short8*)(WsR + j * 16 * 32);
#pragma unroll
        for (int i = 0; i < 4; i++)
#pragma unroll
            for (int j = 0; j < 4; j++)
                acc[i][j] = __builtin_amdgcn_mfma_f32_16x16x32_bf16(af[i], bf_[j], acc[i][j], 0, 0, 0);
        __syncthreads();
        cur ^= 1;
    }
#undef STAGE2

#pragma unroll
    for (int i = 0; i < 4; i++) {
#pragma unroll
        for (int reg = 0; reg < 4; reg++) {
            int lrow = bm + wm + i * 16 + quad * 4 + reg;
            if (lrow >= cnt) continue;
            int tok = tok_list[base + lrow];
            float w = wt_list[base + lrow];
            size_t rowoff = (size_t)tok * HID_;
#pragma unroll
            for (int j = 0; j < 4; j++)
                atomicAdd(&out[rowoff + bn + wn + j * 16 + l15], w * acc[i][j][reg]);
        }
    }
}

// ---------------- Fallback (old) MoE kernels: in-loop fp32->bf16 conversion ----------------
__global__ __launch_bounds__(256) void moe_gemm13_mfma(const float* __restrict__ X,
                                                       const float* __restrict__ w1,
                                                       const float* __restrict__ w3,
                                                       const int* __restrict__ tok_list,
                                                       const int* __restrict__ ebase,
                                                       const int* __restrict__ counts,
                                                       __hip_bfloat16* __restrict__ h13b) {
    int e = blockIdx.z;
    int cnt = counts[e];
    int bm = blockIdx.y * 128;
    if (bm >= cnt) return;
    int base = ebase[e];
    int bn = blockIdx.x * 128;

    __shared__ alignas(16) short Xa[128 * 40];
    __shared__ alignas(16) short W1s[128 * 40];
    __shared__ alignas(16) short W3s[128 * 40];

    int tid = threadIdx.x;
    int sr = tid >> 1;
    int scb = (tid & 1) * 16;

    int lrA = bm + sr;
    int tok = (lrA < cnt) ? tok_list[base + lrA] : 0;
    const float* Arow  = X + (size_t)tok * HID_ + scb;
    const float* B1row = w1 + (size_t)e * INTER_ * HID_ + (size_t)(bn + sr) * HID_ + scb;
    const float* B3row = w3 + (size_t)e * INTER_ * HID_ + (size_t)(bn + sr) * HID_ + scb;
    short* XaW = Xa  + sr * 40 + scb;
    short* W1w = W1s + sr * 40 + scb;
    short* W3w = W3s + sr * 40 + scb;

    int wvid = tid >> 6, lane = tid & 63;
    int wm = (wvid >> 1) * 64, wn = (wvid & 1) * 64;
    int l15 = lane & 15, quad = lane >> 4;

    const short* XaR = Xa  + (wm + l15) * 40 + quad * 8;
    const short* W1r = W1s + (wn + l15) * 40 + quad * 8;
    const short* W3r = W3s + (wn + l15) * 40 + quad * 8;

    floatx4 acc1[4][4], acc3[4][4];
#pragma unroll
    for (int i = 0; i < 4; i++)
#pragma unroll
        for (int j = 0; j < 4; j++) { acc1[i][j] = (floatx4)0.f; acc3[i][j] = (floatx4)0.f; }

    for (int k0 = 0; k0 < HID_; k0 += 32) {
        float4 f0 = *(const float4*)(Arow + k0);
        float4 f1 = *(const float4*)(Arow + k0 + 4);
        float4 f2 = *(const float4*)(Arow + k0 + 8);
        float4 f3 = *(const float4*)(Arow + k0 + 12);
        float4 g0 = *(const float4*)(B1row + k0);
        float4 g1 = *(const float4*)(B1row + k0 + 4);
        float4 g2 = *(const float4*)(B1row + k0 + 8);
        float4 g3 = *(const float4*)(B1row + k0 + 12);
        float4 h0 = *(const float4*)(B3row + k0);
        float4 h1 = *(const float4*)(B3row + k0 + 4);
        float4 h2 = *(const float4*)(B3row + k0 + 8);
        float4 h3 = *(const float4*)(B3row + k0 + 12);
        cvt_store16(XaW, f0, f1, f2, f3);
        cvt_store16(W1w, g0, g1, g2, g3);
        cvt_store16(W3w, h0, h1, h2, h3);
        __syncthreads();

        short8 af[4], b1f[4], b3f[4];
#pragma unroll
        for (int i = 0; i < 4; i++) af[i] = *(const short8*)(XaR + i * 16 * 40);
#pragma unroll
        for (int j = 0; j < 4; j++) {
            b1f[j] = *(const short8*)(W1r + j * 16 * 40);
            b3f[j] = *(const short8*)(W3r + j * 16 * 40);
        }
#pragma unroll
        for (int i = 0; i < 4; i++)
#pragma unroll
            for (int j = 0; j < 4; j++) {
                acc1[i][j] = __builtin_amdgcn_mfma_f32_16x16x32_bf16(af[i], b1f[j], acc1[i][j], 0, 0, 0);
                acc3[i][j] = __builtin_amdgcn_mfma_f32_16x16x32_bf16(af[i], b3f[j], acc3[i][j], 0, 0, 0);
            }
        __syncthreads();
    }

#pragma unroll
    for (int i = 0; i < 4; i++) {
#pragma unroll
        for (int reg = 0; reg < 4; reg++) {
            int lrow = bm + wm + i * 16 + quad * 4 + reg;
            if (lrow >= cnt) continue;
            size_t rowoff = (size_t)(base + lrow) * INTER_;
#pragma unroll
            for (int j = 0; j < 4; j++) {
                float a = acc1[i][j][reg];
                float v = (a / (1.f + __expf(-a))) * acc3[i][j][reg];
                h13b[rowoff + bn + wn + j * 16 + l15] = __float2bfloat16(v);
            }
        }
    }
}

__global__ __launch_bounds__(256) void moe_gemm2_mfma(const __hip_bfloat16* __restrict__ h13b,
                                                      const float* __restrict__ w2,
                                                      const int* __restrict__ tok_list,
                                                      const float* __restrict__ wt_list,
                                                      const int* __restrict__ ebase,
                                                      const int* __restrict__ counts,
                                                      float* __restrict__ out) {
    int e = blockIdx.z;
    int cnt = counts[e];
    int bm = blockIdx.y * 128;
    if (bm >= cnt) return;
    int base = ebase[e];
    int bn = blockIdx.x * 128;

    __shared__ alignas(16) short Xa[128 * 40];
    __shared__ alignas(16) short Ws[128 * 40];

    int tid = threadIdx.x;
    int sr = tid >> 1;
    int scb = (tid & 1) * 16;

    int lrA = bm + sr;
    int slot = base + ((lrA < cnt) ? lrA : 0);
    const short* Arow = (const short*)h13b + (size_t)slot * INTER_ + scb;
    const float* Brow = w2 + (size_t)e * HID_ * INTER_ + (size_t)(bn + sr) * INTER_ + scb;
    short* XaW = Xa + sr * 40 + scb;
    short* WsW = Ws + sr * 40 + scb;

    int wvid = tid >> 6, lane = tid & 63;
    int wm = (wvid >> 1) * 64, wn = (wvid & 1) * 64;
    int l15 = lane & 15, quad = lane >> 4;

    const short* XaR = Xa + (wm + l15) * 40 + quad * 8;
    const short* WsR = Ws + (wn + l15) * 40 + quad * 8;

    floatx4 acc[4][4];
#pragma unroll
    for (int i = 0; i < 4; i++)
#pragma unroll
        for (int j = 0; j < 4; j++) acc[i][j] = (floatx4)0.f;

    for (int k0 = 0; k0 < INTER_; k0 += 32) {
        short8 v0 = *(const short8*)(Arow + k0);
        short8 v1 = *(const short8*)(Arow + k0 + 8);
        float4 g0 = *(const float4*)(Brow + k0);
        float4 g1 = *(const float4*)(Brow + k0 + 4);
        float4 g2 = *(const float4*)(Brow + k0 + 8);
        float4 g3 = *(const float4*)(Brow + k0 + 12);
        *(short8*)XaW = v0;
        *(short8*)(XaW + 8) = v1;
        cvt_store16(WsW, g0, g1, g2, g3);
        __syncthreads();

        short8 af[4], bf_[4];
#pragma unroll
        for (int i = 0; i < 4; i++) af[i] = *(const short8*)(XaR + i * 16 * 40);
#pragma unroll
        for (int j = 0; j < 4; j++) bf_[j] = *(const short8*)(WsR + j * 16 * 40);
#pragma unroll
        for (int i = 0; i < 4; i++)
#pragma unroll
            for (int j = 0; j < 4; j++)
                acc[i][j] = __builtin_amdgcn_mfma_f32_16x16x32_bf16(af[i], bf_[j], acc[i][j], 0, 0, 0);
        __syncthreads();
    }

#pragma unroll
    for (int i = 0; i < 4; i++) {
#pragma unroll
        for (int reg = 0; reg < 4; reg++) {
            int lrow = bm + wm + i * 16 + quad * 4 + reg;
            if (lrow >= cnt) continue;
            int tok = tok_list[base + lrow];
            float w = wt_list[base + lrow];
            size_t rowoff = (size_t)tok * HID_;
#pragma unroll
            for (int j = 0; j < 4; j++)
                atomicAdd(&out[rowoff + bn + wn + j * 16 + l15], w * acc[i][j][reg]);
        }
    }
}

__global__ void copy4_kernel(const float* __restrict__ src, float* __restrict__ dst, int n4) {
    int i = blockIdx.x * blockDim.x + threadIdx.x;
    if (i < n4) ((float4*)dst)[i] = ((const float4*)src)[i];
}

extern "C" void kernel_launch(void* const* d_in, const int* in_sizes, int n_in,
                              void* d_out, int out_size, void* d_ws, size_t ws_size,
                              hipStream_t stream) {
    const float* h      = (const float*)d_in[0];
    const int*   pos    = (const int*)d_in[1];
    const float* wq     = (const float*)d_in[2];
    const float* wk     = (const float*)d_in[3];
    const float* wv     = (const float*)d_in[4];
    const float* wo     = (const float*)d_in[5];
    const float* gate_w = (const float*)d_in[6];
    const float* w1     = (const float*)d_in[7];
    const float* w2     = (const float*)d_in[8];
    const float* w3     = (const float*)d_in[9];
    const float* ln1_w  = (const float*)d_in[10];
    const float* ln2_w  = (const float*)d_in[11];
    float* out = (float*)d_out;

    float* ws = (float*)d_ws;
    const size_t M1 = 1024 * 1024;
    float* xn1 = ws;                 // 2M floats (alias: ob)
    float* ob  = ws;
    float* qb  = ws + 2 * M1;        // 2M (alias: h2)
    float* h2  = ws + 2 * M1;
    float* kb  = ws + 4 * M1;        // 0.5M
    float* vb  = ws + 4 * M1 + M1 / 2; // 0.5M
    float* xn2 = ws + 5 * M1;        // 2M
    __hip_bfloat16* h13b = (__hip_bfloat16*)(ws + 7 * M1);  // 4096*3584 bf16
    float* smallf = ws + 14 * M1 + M1 / 2;
    int*   sel      = (int*)smallf;
    float* wtb      = smallf + 4096;
    int*   counts   = (int*)(smallf + 8192);
    int*   ebase    = (int*)(smallf + 8192 + 16);
    int*   cursor   = (int*)(smallf + 8192 + 32);
    int*   tok_list = (int*)(smallf + 8192 + 64);
    float* wt_list  = smallf + 8192 + 64 + 4352;

    // new-path bf16 staging buffers (beyond 15M floats)
    const size_t WELEM = (size_t)E_ * INTER_ * HID_;       // 29,360,128 bf16 elems per weight
    short* xn2b = (short*)(ws + 15 * M1);                  // T*HID bf16 = 1M floats
    short* w1bb = (short*)(ws + 16 * M1);                  // WELEM bf16
    short* w3bb = w1bb + WELEM;                            // WELEM bf16
    short* w2bb = w1bb;                                    // reuse w1b slot after gemm13
    const size_t need_bytes = (16 * M1 + WELEM) * sizeof(float);  // ~184.5 MB
    bool big = ws_size >= need_bytes;

    hipLaunchKernelGGL(init_counts_kernel, dim3(1), dim3(64), 0, stream, counts);
    hipLaunchKernelGGL(rmsnorm_kernel, dim3(T_), dim3(256), 0, stream, h, ln1_w, xn1);
    hipLaunchKernelGGL(gemm_f32, dim3(16, 32), dim3(256), 0, stream, xn1, wq, qb, (const float*)nullptr, T_, NH_ * HD_, HID_);
    hipLaunchKernelGGL(gemm_f32, dim3(4, 32),  dim3(256), 0, stream, xn1, wk, kb, (const float*)nullptr, T_, NKV_ * HD_, HID_);
    hipLaunchKernelGGL(gemm_f32, dim3(4, 32),  dim3(256), 0, stream, xn1, wv, vb, (const float*)nullptr, T_, NKV_ * HD_, HID_);
    {
        int tot = T_ * (NH_ + NKV_) * 32;
        hipLaunchKernelGGL(rope_kernel, dim3((tot + 255) / 256), dim3(256), 0, stream, qb, kb, pos);
    }
    hipLaunchKernelGGL(flash_attn_kernel, dim3(32 * 16), dim3(256), 0, stream, qb, kb, vb, ob);
    hipLaunchKernelGGL(gemm_f32, dim3(16, 32), dim3(256), 0, stream, ob, wo, h2, h, T_, HID_, NH_ * HD_);
    hipLaunchKernelGGL(rmsnorm_kernel, dim3(T_), dim3(256), 0, stream, h2, ln2_w, xn2);
    hipLaunchKernelGGL(gating_kernel, dim3(T_), dim3(64), 0, stream, xn2, gate_w, sel, wtb, counts);
    hipLaunchKernelGGL(prefix_kernel, dim3(1), dim3(64), 0, stream, counts, ebase, cursor);
    hipLaunchKernelGGL(scatter_kernel, dim3((T_ + 255) / 256), dim3(256), 0, stream, sel, wtb, cursor, tok_list, wt_list);

    if (big) {
        // pre-convert (RNE, bit-identical to old in-loop cvt), then async-pipelined bf16 GEMMs
        const int n8w = (int)(WELEM / 8);
        hipLaunchKernelGGL(cvt_bf16_kernel, dim3(2048), dim3(256), 0, stream, w1, w1bb, n8w);
        hipLaunchKernelGGL(cvt_bf16_kernel, dim3(2048), dim3(256), 0, stream, w3, w3bb, n8w);
        hipLaunchKernelGGL(cvt_bf16_kernel, dim3(256),  dim3(256), 0, stream, xn2, xn2b, T_ * HID_ / 8);
        hipLaunchKernelGGL(moe_gemm13_v2, dim3(INTER_ / 128, 16, E_), dim3(256), 0, stream,
                           xn2b, w1bb, w3bb, tok_list, ebase, counts, h13b);
        hipLaunchKernelGGL(cvt_bf16_kernel, dim3(2048), dim3(256), 0, stream, w2, w2bb, n8w);  // overwrites w1bb
        hipLaunchKernelGGL(copy4_kernel, dim3((T_ * HID_ / 4 + 255) / 256), dim3(256), 0, stream, h2, out, T_ * HID_ / 4);
        hipLaunchKernelGGL(moe_gemm2_v2, dim3(HID_ / 128, 16, E_), dim3(256), 0, stream,
                           (const short*)h13b, w2bb, tok_list, wt_list, ebase, counts, out);
    } else {
        hipLaunchKernelGGL(moe_gemm13_mfma, dim3(INTER_ / 128, 16, E_), dim3(256), 0, stream,
                           xn2, w1, w3, tok_list, ebase, counts, h13b);
        hipLaunchKernelGGL(copy4_kernel, dim3((T_ * HID_ / 4 + 255) / 256), dim3(256), 0, stream, h2, out, T_ * HID_ / 4);
        hipLaunchKernelGGL(moe_gemm2_mfma, dim3(HID_ / 128, 16, E_), dim3(256), 0, stream,
                           h13b, w2, tok_list, wt_list, ebase, counts, out);
    }
}

// Round 3
// 1442.485 us; speedup vs baseline: 1.2366x; 1.1135x over previous
//
#include <hip/hip_runtime.h>
#include <hip/hip_bf16.h>
#include <math.h>

#define T_    2048
#define HID_  1024
#define NH_   16
#define NKV_  4
#define HD_   64
#define E_    8
#define TOPK_ 2
#define INTER_ 3584
#define EPS_  1e-6f

typedef __attribute__((ext_vector_type(8))) short short8;
typedef __attribute__((ext_vector_type(4))) float floatx4;

__device__ inline short f2bf(float f) {
    __hip_bfloat16 b = __float2bfloat16(f);
    return *reinterpret_cast<short*>(&b);
}

__device__ inline void cvt_store16(short* dst, float4 a, float4 b, float4 c, float4 d) {
    short8 lo, hi;
    lo[0] = f2bf(a.x); lo[1] = f2bf(a.y); lo[2] = f2bf(a.z); lo[3] = f2bf(a.w);
    lo[4] = f2bf(b.x); lo[5] = f2bf(b.y); lo[6] = f2bf(b.z); lo[7] = f2bf(b.w);
    hi[0] = f2bf(c.x); hi[1] = f2bf(c.y); hi[2] = f2bf(c.z); hi[3] = f2bf(c.w);
    hi[4] = f2bf(d.x); hi[5] = f2bf(d.y); hi[6] = f2bf(d.z); hi[7] = f2bf(d.w);
    *(short8*)dst = lo;
    *(short8*)(dst + 8) = hi;
}

// async global->LDS, 16B per lane. LDS dest must be wave-uniform-base + lane*16.
__device__ inline void async_copy16(short* lds, const short* g) {
    __builtin_amdgcn_global_load_lds((const __attribute__((address_space(1))) void*)g,
                                     (__attribute__((address_space(3))) void*)lds, 16, 0, 0);
}

// ---------------- RMSNorm: one block (256 thr) per row ----------------
__global__ __launch_bounds__(256) void rmsnorm_kernel(const float* __restrict__ x,
                                                      const float* __restrict__ w,
                                                      float* __restrict__ o) {
    int t = blockIdx.x;
    const float* xr = x + (size_t)t * HID_;
    float s = 0.f;
    for (int d = threadIdx.x; d < HID_; d += 256) { float v = xr[d]; s += v * v; }
    __shared__ float red[256];
    red[threadIdx.x] = s; __syncthreads();
    for (int off = 128; off > 0; off >>= 1) {
        if (threadIdx.x < off) red[threadIdx.x] += red[threadIdx.x + off];
        __syncthreads();
    }
    float inv = rsqrtf(red[0] / (float)HID_ + EPS_);
    for (int d = threadIdx.x; d < HID_; d += 256)
        o[(size_t)t * HID_ + d] = w[d] * xr[d] * inv;
}

// ---------------- Generic fp32 GEMM: C[M,N] = A[M,K] @ B[N,K]^T (+add) ----------------
__global__ __launch_bounds__(256) void gemm_f32(const float* __restrict__ A,
                                                const float* __restrict__ B,
                                                float* __restrict__ C,
                                                const float* __restrict__ addsrc,
                                                int M, int N, int K) {
    __shared__ float As[16][65];
    __shared__ float Bs[16][65];
    int tid = threadIdx.x;
    int tx = tid & 15, ty = tid >> 4;
    int bm = blockIdx.y * 64, bn = blockIdx.x * 64;
    float acc[4][4];
#pragma unroll
    for (int i = 0; i < 4; i++)
#pragma unroll
        for (int j = 0; j < 4; j++) acc[i][j] = 0.f;

    int mL[4], kL[4];
#pragma unroll
    for (int l = 0; l < 4; l++) { int idx = tid + l * 256; mL[l] = idx >> 4; kL[l] = idx & 15; }

    for (int k0 = 0; k0 < K; k0 += 16) {
#pragma unroll
        for (int l = 0; l < 4; l++) {
            int m = mL[l], kk = kL[l];
            int gr = bm + m;
            As[kk][m] = (gr < M) ? A[(size_t)gr * K + k0 + kk] : 0.f;
            int gc = bn + m;
            Bs[kk][m] = (gc < N) ? B[(size_t)gc * K + k0 + kk] : 0.f;
        }
        __syncthreads();
#pragma unroll
        for (int kk = 0; kk < 16; kk++) {
            float a[4], b[4];
#pragma unroll
            for (int i = 0; i < 4; i++) a[i] = As[kk][ty * 4 + i];
#pragma unroll
            for (int j = 0; j < 4; j++) b[j] = Bs[kk][tx * 4 + j];
#pragma unroll
            for (int i = 0; i < 4; i++)
#pragma unroll
                for (int j = 0; j < 4; j++) acc[i][j] += a[i] * b[j];
        }
        __syncthreads();
    }
#pragma unroll
    for (int i = 0; i < 4; i++) {
        int r = bm + ty * 4 + i;
        if (r >= M) continue;
#pragma unroll
        for (int j = 0; j < 4; j++) {
            int c = bn + tx * 4 + j;
            if (c >= N) continue;
            float v = acc[i][j];
            if (addsrc) v += addsrc[(size_t)r * N + c];
            C[(size_t)r * N + c] = v;
        }
    }
}

// ---------------- RoPE in-place on q and k ----------------
__global__ void rope_kernel(float* __restrict__ qb, float* __restrict__ kb,
                            const int* __restrict__ pos_ids) {
    int idx = blockIdx.x * blockDim.x + threadIdx.x;
    const int totq = T_ * NH_ * 32;
    const int totk = T_ * NKV_ * 32;
    if (idx >= totq + totk) return;
    float* buf; int t, hh, i, hw;
    if (idx < totq) { buf = qb; hw = NH_;  t = idx / (NH_ * 32); int r = idx % (NH_ * 32); hh = r / 32; i = r % 32; }
    else { idx -= totq; buf = kb; hw = NKV_; t = idx / (NKV_ * 32); int r = idx % (NKV_ * 32); hh = r / 32; i = r % 32; }
    float pos = (float)pos_ids[t];
    float inv = expf(-(float)i * (13.815510558f / 32.0f));
    float fr = pos * inv;
    float c = cosf(fr), s = sinf(fr);
    size_t base = (size_t)t * hw * 64 + (size_t)hh * 64;
    float x1 = buf[base + i], x2 = buf[base + i + 32];
    buf[base + i]      = x1 * c - x2 * s;
    buf[base + i + 32] = x2 * c + x1 * s;
}

// ---------------- Flash attention v2: bf16 MFMA ----------------
// One block per (head, 64-row q-tile), zigzag qt order for causal load balance.
// 4 waves; wave w owns q-rows [q0+16w, q0+16w+16). Q in registers.
// K staged [n][d] (80-short stride), V staged transposed [d][n].
// P bf16 in wave-private LDS rows -> no barrier between P write and PV read
// (same-wave DS ordering; lgkmcnt(0) fence blocks compiler reorder).
// T14: next tile's K/V global loads issued before compute phase.
__global__ __launch_bounds__(256) void flash_attn_mfma(const short* __restrict__ qbh,
                                                       const short* __restrict__ kbh,
                                                       const short* __restrict__ vbh,
                                                       float* __restrict__ ob) {
    __shared__ alignas(16) short Ks[64][80];
    __shared__ alignas(16) short Vt[64][80];
    __shared__ alignas(16) short Ps[64][80];

    int bid = blockIdx.x;
    int h = bid & 15;
    int qr = bid >> 4;
    int qt = (qr & 1) ? (31 - (qr >> 1)) : (qr >> 1);
    int q0 = qt * 64;
    int kvh = h >> 2;
    int tid = threadIdx.x;
    int w = tid >> 6, lane = tid & 63;
    int l15 = lane & 15, quad = lane >> 4;
    int str = tid >> 2, stc = tid & 3;     // staging: row 0..63, 16B chunk 0..3

    // Q fragments in registers: rows q0+16w+l15, k-chunks 0..31 / 32..63
    short8 aq0, aq1;
    {
        const short* qrow = qbh + (size_t)(q0 + 16 * w + l15) * (NH_ * HD_) + h * HD_ + quad * 8;
        aq0 = *(const short8*)(qrow);
        aq1 = *(const short8*)(qrow + 32);
    }

    floatx4 o_acc[4];
    float m_i[4], l_i[4];
#pragma unroll
    for (int j = 0; j < 4; j++) o_acc[j] = (floatx4)0.f;
#pragma unroll
    for (int r = 0; r < 4; r++) { m_i[r] = -INFINITY; l_i[r] = 0.f; }

    int nt = q0 / 64 + 1;

    // prologue: load tile 0 K/V into regs
    const short* kg = kbh + (size_t)str * (NKV_ * HD_) + kvh * HD_ + stc * 8;
    const short* vg = vbh + (size_t)str * (NKV_ * HD_) + kvh * HD_ + stc * 8;
    short8 kr0 = *(const short8*)kg;
    short8 kr1 = *(const short8*)(kg + 32);
    short8 vr0 = *(const short8*)vg;
    short8 vr1 = *(const short8*)(vg + 32);

    for (int it = 0; it < nt; ++it) {
        int t0 = it * 64;
        __syncthreads();                       // Ks/Vt free (prev tile's reads done)
        // write staged regs -> LDS
        *(short8*)&Ks[str][stc * 8]      = kr0;
        *(short8*)&Ks[str][32 + stc * 8] = kr1;
#pragma unroll
        for (int i = 0; i < 8; i++) {
            Vt[stc * 8 + i][str]      = vr0[i];
            Vt[32 + stc * 8 + i][str] = vr1[i];
        }
        // T14: issue next tile's global loads now; latency hides under compute
        if (it + 1 < nt) {
            const short* kgn = kbh + (size_t)(t0 + 64 + str) * (NKV_ * HD_) + kvh * HD_ + stc * 8;
            const short* vgn = vbh + (size_t)(t0 + 64 + str) * (NKV_ * HD_) + kvh * HD_ + stc * 8;
            kr0 = *(const short8*)kgn;
            kr1 = *(const short8*)(kgn + 32);
            vr0 = *(const short8*)vgn;
            vr1 = *(const short8*)(vgn + 32);
        }
        __syncthreads();                       // Ks/Vt staged

        // S = Q K^T  (C: row m=quad*4+reg, col n=16j+l15)
        floatx4 s[4];
#pragma unroll
        for (int j = 0; j < 4; j++) s[j] = (floatx4)0.f;
        __builtin_amdgcn_s_setprio(1);
#pragma unroll
        for (int j = 0; j < 4; j++) {
            short8 bk0 = *(const short8*)&Ks[16 * j + l15][quad * 8];
            short8 bk1 = *(const short8*)&Ks[16 * j + l15][32 + quad * 8];
            s[j] = __builtin_amdgcn_mfma_f32_16x16x32_bf16(aq0, bk0, s[j], 0, 0, 0);
            s[j] = __builtin_amdgcn_mfma_f32_16x16x32_bf16(aq1, bk1, s[j], 0, 0, 0);
        }
        __builtin_amdgcn_s_setprio(0);

        bool diag = (t0 == q0);
#pragma unroll
        for (int j = 0; j < 4; j++)
#pragma unroll
            for (int reg = 0; reg < 4; reg++) {
                s[j][reg] *= 0.125f;
                if (diag && (16 * j + l15 > 16 * w + quad * 4 + reg)) s[j][reg] = -INFINITY;
            }

        // online softmax; row (quad*4+reg) held by the 16 lanes sharing quad
#pragma unroll
        for (int reg = 0; reg < 4; reg++) {
            float mx = fmaxf(fmaxf(s[0][reg], s[1][reg]), fmaxf(s[2][reg], s[3][reg]));
#pragma unroll
            for (int off = 8; off >= 1; off >>= 1) mx = fmaxf(mx, __shfl_xor(mx, off));
            float mn = fmaxf(m_i[reg], mx);
            float alpha = __expf(m_i[reg] - mn);
            float rs = 0.f;
#pragma unroll
            for (int j = 0; j < 4; j++) { float p = __expf(s[j][reg] - mn); s[j][reg] = p; rs += p; }
#pragma unroll
            for (int off = 8; off >= 1; off >>= 1) rs += __shfl_xor(rs, off);
            l_i[reg] = l_i[reg] * alpha + rs;
            m_i[reg] = mn;
#pragma unroll
            for (int j = 0; j < 4; j++) o_acc[j][reg] *= alpha;
        }

        // P -> bf16, wave-private LDS rows [16w, 16w+16)
#pragma unroll
        for (int j = 0; j < 4; j++)
#pragma unroll
            for (int reg = 0; reg < 4; reg++)
                Ps[16 * w + quad * 4 + reg][16 * j + l15] = f2bf(s[j][reg]);
        __asm__ volatile("s_waitcnt lgkmcnt(0)" ::: "memory");   // same-wave write->read fence

        short8 ap0 = *(const short8*)&Ps[16 * w + l15][quad * 8];
        short8 ap1 = *(const short8*)&Ps[16 * w + l15][32 + quad * 8];
        __builtin_amdgcn_s_setprio(1);
#pragma unroll
        for (int j = 0; j < 4; j++) {
            short8 bv0 = *(const short8*)&Vt[16 * j + l15][quad * 8];
            short8 bv1 = *(const short8*)&Vt[16 * j + l15][32 + quad * 8];
            o_acc[j] = __builtin_amdgcn_mfma_f32_16x16x32_bf16(ap0, bv0, o_acc[j], 0, 0, 0);
            o_acc[j] = __builtin_amdgcn_mfma_f32_16x16x32_bf16(ap1, bv1, o_acc[j], 0, 0, 0);
        }
        __builtin_amdgcn_s_setprio(0);
    }

    // epilogue: O row = q0+16w+quad*4+reg, col d = 16j+l15
#pragma unroll
    for (int reg = 0; reg < 4; reg++) {
        float invl = 1.f / l_i[reg];
        size_t rbase = (size_t)(q0 + 16 * w + quad * 4 + reg) * (NH_ * HD_) + h * HD_;
#pragma unroll
        for (int j = 0; j < 4; j++)
            ob[rbase + 16 * j + l15] = o_acc[j][reg] * invl;
    }
}

// ---------------- Flash attention (fp32 fallback) ----------------
__global__ __launch_bounds__(256) void flash_attn_kernel(const float* __restrict__ qb,
                                                         const float* __restrict__ kb,
                                                         const float* __restrict__ vb,
                                                         float* __restrict__ ob) {
    __shared__ float Qs[64][68];
    __shared__ float Ks[64][68];
    __shared__ float Vs[64][68];
    __shared__ float Ps[64][68];

    int bid = blockIdx.x;
    int h = bid & 15;
    int qr = bid >> 4;
    int qt = (qr & 1) ? (31 - (qr >> 1)) : (qr >> 1);
    int q0 = qt * 64;
    int kvh = h >> 2;
    int tid = threadIdx.x;
    int tx = tid & 15, ty = tid >> 4;

#pragma unroll
    for (int l = 0; l < 16; l++) {
        int idx = l * 256 + tid;
        int m = idx >> 6, d = idx & 63;
        Qs[d][m] = qb[(size_t)(q0 + m) * (NH_ * HD_) + h * HD_ + d];
    }

    float o_acc[4][4];
    float m_i[4], l_i[4];
#pragma unroll
    for (int i = 0; i < 4; i++) {
        m_i[i] = -INFINITY; l_i[i] = 0.f;
#pragma unroll
        for (int j = 0; j < 4; j++) o_acc[i][j] = 0.f;
    }

    for (int t0 = 0; t0 <= q0; t0 += 64) {
        __syncthreads();
#pragma unroll
        for (int l = 0; l < 16; l++) {
            int idx = l * 256 + tid;
            int m = idx >> 6, d = idx & 63;
            size_t g = (size_t)(t0 + m) * (NKV_ * HD_) + kvh * HD_ + d;
            Ks[d][m] = kb[g];
            Vs[m][d] = vb[g];
        }
        __syncthreads();

        float s[4][4];
#pragma unroll
        for (int i = 0; i < 4; i++)
#pragma unroll
            for (int j = 0; j < 4; j++) s[i][j] = 0.f;
#pragma unroll 4
        for (int kk = 0; kk < 64; kk++) {
            float4 a4 = *(const float4*)&Qs[kk][ty * 4];
            float4 b4 = *(const float4*)&Ks[kk][tx * 4];
            float a[4] = {a4.x, a4.y, a4.z, a4.w};
            float b[4] = {b4.x, b4.y, b4.z, b4.w};
#pragma unroll
            for (int i = 0; i < 4; i++)
#pragma unroll
                for (int j = 0; j < 4; j++) s[i][j] += a[i] * b[j];
        }

        bool diag = (t0 == q0);
#pragma unroll
        for (int i = 0; i < 4; i++) {
#pragma unroll
            for (int j = 0; j < 4; j++) {
                s[i][j] *= 0.125f;
                if (diag && (t0 + tx * 4 + j > q0 + ty * 4 + i)) s[i][j] = -INFINITY;
            }
        }

#pragma unroll
        for (int i = 0; i < 4; i++) {
            float mx = fmaxf(fmaxf(s[i][0], s[i][1]), fmaxf(s[i][2], s[i][3]));
#pragma unroll
            for (int off = 8; off >= 1; off >>= 1) mx = fmaxf(mx, __shfl_xor(mx, off));
            float mn = fmaxf(m_i[i], mx);
            float alpha = __expf(m_i[i] - mn);
            float rs = 0.f;
#pragma unroll
            for (int j = 0; j < 4; j++) { float p = __expf(s[i][j] - mn); s[i][j] = p; rs += p; }
#pragma unroll
            for (int off = 8; off >= 1; off >>= 1) rs += __shfl_xor(rs, off);
            l_i[i] = l_i[i] * alpha + rs;
            m_i[i] = mn;
#pragma unroll
            for (int j = 0; j < 4; j++) o_acc[i][j] *= alpha;
        }

#pragma unroll
        for (int j = 0; j < 4; j++)
#pragma unroll
            for (int i = 0; i < 4; i++)
                Ps[tx * 4 + j][ty * 4 + i] = s[i][j];
        __syncthreads();

#pragma unroll 4
        for (int kk = 0; kk < 64; kk++) {
            float4 a4 = *(const float4*)&Ps[kk][ty * 4];
            float4 b4 = *(const float4*)&Vs[kk][tx * 4];
            float a[4] = {a4.x, a4.y, a4.z, a4.w};
            float b[4] = {b4.x, b4.y, b4.z, b4.w};
#pragma unroll
            for (int i = 0; i < 4; i++)
#pragma unroll
                for (int j = 0; j < 4; j++) o_acc[i][j] += a[i] * b[j];
        }
    }

#pragma unroll
    for (int i = 0; i < 4; i++) {
        float invl = 1.f / l_i[i];
        int r = q0 + ty * 4 + i;
#pragma unroll
        for (int j = 0; j < 4; j++)
            ob[(size_t)r * (NH_ * HD_) + h * HD_ + tx * 4 + j] = o_acc[i][j] * invl;
    }
}

// ---------------- Gating: one wave per token ----------------
__global__ __launch_bounds__(64) void gating_kernel(const float* __restrict__ xn2,
                                                    const float* __restrict__ gate_w,
                                                    int* __restrict__ sel,
                                                    float* __restrict__ wt,
                                                    int* __restrict__ counts) {
    int t = blockIdx.x, lane = threadIdx.x;
    const float* x = xn2 + (size_t)t * HID_;
    float logits[E_];
    for (int e = 0; e < E_; e++) {
        float p = 0.f;
        for (int d = lane; d < HID_; d += 64) p += x[d] * gate_w[(size_t)e * HID_ + d];
#pragma unroll
        for (int off = 32; off > 0; off >>= 1) p += __shfl_xor(p, off);
        logits[e] = p;
    }
    float mx = logits[0];
    for (int e = 1; e < E_; e++) mx = fmaxf(mx, logits[e]);
    float pr[E_]; float sum = 0.f;
    for (int e = 0; e < E_; e++) { pr[e] = __expf(logits[e] - mx); sum += pr[e]; }
    int e1 = 0; float p1 = pr[0];
    for (int e = 1; e < E_; e++) if (pr[e] > p1) { p1 = pr[e]; e1 = e; }
    int e2 = -1; float p2 = -1.f;
    for (int e = 0; e < E_; e++) if (e != e1 && pr[e] > p2) { p2 = pr[e]; e2 = e; }
    if (lane == 0) {
        float denom = p1 + p2;
        sel[t * 2] = e1; sel[t * 2 + 1] = e2;
        wt[t * 2] = p1 / denom; wt[t * 2 + 1] = p2 / denom;
        atomicAdd(&counts[e1], 1);
        atomicAdd(&counts[e2], 1);
    }
}

__global__ void init_counts_kernel(int* counts) {
    if (threadIdx.x < E_) counts[threadIdx.x] = 0;
}

__global__ void prefix_kernel(const int* __restrict__ counts, int* __restrict__ ebase,
                              int* __restrict__ cursor) {
    if (threadIdx.x == 0) {
        int b = 0;
        for (int e = 0; e < E_; e++) { ebase[e] = b; cursor[e] = b; b += counts[e]; }
    }
}

__global__ void scatter_kernel(const int* __restrict__ sel, const float* __restrict__ wt,
                               int* __restrict__ cursor, int* __restrict__ tok_list,
                               float* __restrict__ wt_list) {
    int t = blockIdx.x * blockDim.x + threadIdx.x;
    if (t >= T_) return;
    for (int j = 0; j < 2; j++) {
        int e = sel[t * 2 + j];
        float w = wt[t * 2 + j];
        int p = atomicAdd(&cursor[e], 1);
        tok_list[p] = t;
        wt_list[p] = w;
    }
}

// ---------------- fp32 -> bf16 bulk convert (RNE, memory-bound) ----------------
__global__ __launch_bounds__(256) void cvt_bf16_kernel(const float* __restrict__ src,
                                                       short* __restrict__ dst, int n8) {
    int stride = gridDim.x * blockDim.x;
    for (int i = blockIdx.x * blockDim.x + threadIdx.x; i < n8; i += stride) {
        float4 a = ((const float4*)src)[2 * i];
        float4 b = ((const float4*)src)[2 * i + 1];
        short8 o;
        o[0] = f2bf(a.x); o[1] = f2bf(a.y); o[2] = f2bf(a.z); o[3] = f2bf(a.w);
        o[4] = f2bf(b.x); o[5] = f2bf(b.y); o[6] = f2bf(b.z); o[7] = f2bf(b.w);
        ((short8*)dst)[i] = o;
    }
}

// ---------------- MoE GEMM 1&3 v2: bf16 inputs, global_load_lds, 2-phase pipeline ----------------
__global__ __launch_bounds__(256, 2) void moe_gemm13_v2(const short* __restrict__ Xb,
                                                        const short* __restrict__ w1b,
                                                        const short* __restrict__ w3b,
                                                        const int* __restrict__ tok_list,
                                                        const int* __restrict__ ebase,
                                                        const int* __restrict__ counts,
                                                        __hip_bfloat16* __restrict__ h13b) {
    int e = blockIdx.z;
    int cnt = counts[e];
    int bm = blockIdx.y * 128;
    if (cnt <= 0 || bm >= cnt) return;
    int base = ebase[e];
    int bn = blockIdx.x * 128;

    __shared__ alignas(16) short lds[2][3][128 * 32];  // 48 KiB

    int tid = threadIdx.x;
    int sr = tid >> 2;
    int sc = (tid & 3) * 8;
    int ldst = tid * 8;

    int lr0 = bm + sr, lr1 = bm + sr + 64;
    int tok0 = tok_list[base + (lr0 < cnt ? lr0 : cnt - 1)];
    int tok1 = tok_list[base + (lr1 < cnt ? lr1 : cnt - 1)];
    const short* aG0 = Xb + (size_t)tok0 * HID_ + sc;
    const short* aG1 = Xb + (size_t)tok1 * HID_ + sc;
    const short* b1G0 = w1b + (size_t)e * INTER_ * HID_ + (size_t)(bn + sr) * HID_ + sc;
    const short* b1G1 = b1G0 + (size_t)64 * HID_;
    const short* b3G0 = w3b + (size_t)e * INTER_ * HID_ + (size_t)(bn + sr) * HID_ + sc;
    const short* b3G1 = b3G0 + (size_t)64 * HID_;

    int wvid = tid >> 6, lane = tid & 63;
    int wm = (wvid >> 1) * 64, wn = (wvid & 1) * 64;
    int l15 = lane & 15, quad = lane >> 4;

    floatx4 acc1[4][4], acc3[4][4];
#pragma unroll
    for (int i = 0; i < 4; i++)
#pragma unroll
        for (int j = 0; j < 4; j++) { acc1[i][j] = (floatx4)0.f; acc3[i][j] = (floatx4)0.f; }

#define STAGE13(b, k0) do {                                          \
        async_copy16(&lds[b][0][ldst],        aG0 + (k0));           \
        async_copy16(&lds[b][0][ldst + 2048], aG1 + (k0));           \
        async_copy16(&lds[b][1][ldst],        b1G0 + (k0));          \
        async_copy16(&lds[b][1][ldst + 2048], b1G1 + (k0));          \
        async_copy16(&lds[b][2][ldst],        b3G0 + (k0));          \
        async_copy16(&lds[b][2][ldst + 2048], b3G1 + (k0));          \
    } while (0)

    STAGE13(0, 0);
    __syncthreads();

    int cur = 0;
    for (int k0 = 0; k0 < HID_; k0 += 32) {
        if (k0 + 32 < HID_) STAGE13(cur ^ 1, k0 + 32);

        const short* XaR = &lds[cur][0][(wm + l15) * 32 + quad * 8];
        const short* W1r = &lds[cur][1][(wn + l15) * 32 + quad * 8];
        const short* W3r = &lds[cur][2][(wn + l15) * 32 + quad * 8];
        short8 af[4], b1f[4], b3f[4];
#pragma unroll
        for (int i = 0; i < 4; i++) af[i] = *(const short8*)(XaR + i * 16 * 32);
#pragma unroll
        for (int j = 0; j < 4; j++) {
            b1f[j] = *(const short8*)(W1r + j * 16 * 32);
            b3f[j] = *(const short8*)(W3r + j * 16 * 32);
        }
#pragma unroll
        for (int i = 0; i < 4; i++)
#pragma unroll
            for (int j = 0; j < 4; j++) {
                acc1[i][j] = __builtin_amdgcn_mfma_f32_16x16x32_bf16(af[i], b1f[j], acc1[i][j], 0, 0, 0);
                acc3[i][j] = __builtin_amdgcn_mfma_f32_16x16x32_bf16(af[i], b3f[j], acc3[i][j], 0, 0, 0);
            }
        __syncthreads();
        cur ^= 1;
    }
#undef STAGE13

#pragma unroll
    for (int i = 0; i < 4; i++) {
#pragma unroll
        for (int reg = 0; reg < 4; reg++) {
            int lrow = bm + wm + i * 16 + quad * 4 + reg;
            if (lrow >= cnt) continue;
            size_t rowoff = (size_t)(base + lrow) * INTER_;
#pragma unroll
            for (int j = 0; j < 4; j++) {
                float a = acc1[i][j][reg];
                float v = (a / (1.f + __expf(-a))) * acc3[i][j][reg];
                h13b[rowoff + bn + wn + j * 16 + l15] = __float2bfloat16(v);
            }
        }
    }
}

// ---------------- MoE GEMM 2 v2: out[tok] += wt * (h13b @ w2b^T) ----------------
__global__ __launch_bounds__(256, 2) void moe_gemm2_v2(const short* __restrict__ h13s,
                                                       const short* __restrict__ w2b,
                                                       const int* __restrict__ tok_list,
                                                       const float* __restrict__ wt_list,
                                                       const int* __restrict__ ebase,
                                                       const int* __restrict__ counts,
                                                       float* __restrict__ out) {
    int e = blockIdx.z;
    int cnt = counts[e];
    int bm = blockIdx.y * 128;
    if (cnt <= 0 || bm >= cnt) return;
    int base = ebase[e];
    int bn = blockIdx.x * 128;

    __shared__ alignas(16) short lds[2][2][128 * 32];  // 32 KiB

    int tid = threadIdx.x;
    int sr = tid >> 2;
    int sc = (tid & 3) * 8;
    int ldst = tid * 8;

    int lr0 = bm + sr, lr1 = bm + sr + 64;
    int slot0 = base + (lr0 < cnt ? lr0 : cnt - 1);
    int slot1 = base + (lr1 < cnt ? lr1 : cnt - 1);
    const short* aG0 = h13s + (size_t)slot0 * INTER_ + sc;
    const short* aG1 = h13s + (size_t)slot1 * INTER_ + sc;
    const short* bG0 = w2b + (size_t)e * HID_ * INTER_ + (size_t)(bn + sr) * INTER_ + sc;
    const short* bG1 = bG0 + (size_t)64 * INTER_;

    int wvid = tid >> 6, lane = tid & 63;
    int wm = (wvid >> 1) * 64, wn = (wvid & 1) * 64;
    int l15 = lane & 15, quad = lane >> 4;

    floatx4 acc[4][4];
#pragma unroll
    for (int i = 0; i < 4; i++)
#pragma unroll
        for (int j = 0; j < 4; j++) acc[i][j] = (floatx4)0.f;

#define STAGE2(b, k0) do {                                          \
        async_copy16(&lds[b][0][ldst],        aG0 + (k0));          \
        async_copy16(&lds[b][0][ldst + 2048], aG1 + (k0));          \
        async_copy16(&lds[b][1][ldst],        bG0 + (k0));          \
        async_copy16(&lds[b][1][ldst + 2048], bG1 + (k0));          \
    } while (0)

    STAGE2(0, 0);
    __syncthreads();

    int cur = 0;
    for (int k0 = 0; k0 < INTER_; k0 += 32) {
        if (k0 + 32 < INTER_) STAGE2(cur ^ 1, k0 + 32);

        const short* XaR = &lds[cur][0][(wm + l15) * 32 + quad * 8];
        const short* WsR = &lds[cur][1][(wn + l15) * 32 + quad * 8];
        short8 af[4], bf_[4];
#pragma unroll
        for (int i = 0; i < 4; i++) af[i] = *(const short8*)(XaR + i * 16 * 32);
#pragma unroll
        for (int j = 0; j < 4; j++) bf_[j] = *(const short8*)(WsR + j * 16 * 32);
#pragma unroll
        for (int i = 0; i < 4; i++)
#pragma unroll
            for (int j = 0; j < 4; j++)
                acc[i][j] = __builtin_amdgcn_mfma_f32_16x16x32_bf16(af[i], bf_[j], acc[i][j], 0, 0, 0);
        __syncthreads();
        cur ^= 1;
    }
#undef STAGE2

#pragma unroll
    for (int i = 0; i < 4; i++) {
#pragma unroll
        for (int reg = 0; reg < 4; reg++) {
            int lrow = bm + wm + i * 16 + quad * 4 + reg;
            if (lrow >= cnt) continue;
            int tok = tok_list[base + lrow];
            float w = wt_list[base + lrow];
            size_t rowoff = (size_t)tok * HID_;
#pragma unroll
            for (int j = 0; j < 4; j++)
                atomicAdd(&out[rowoff + bn + wn + j * 16 + l15], w * acc[i][j][reg]);
        }
    }
}

// ---------------- Fallback (old) MoE kernels ----------------
__global__ __launch_bounds__(256) void moe_gemm13_mfma(const float* __restrict__ X,
                                                       const float* __restrict__ w1,
                                                       const float* __restrict__ w3,
                                                       const int* __restrict__ tok_list,
                                                       const int* __restrict__ ebase,
                                                       const int* __restrict__ counts,
                                                       __hip_bfloat16* __restrict__ h13b) {
    int e = blockIdx.z;
    int cnt = counts[e];
    int bm = blockIdx.y * 128;
    if (bm >= cnt) return;
    int base = ebase[e];
    int bn = blockIdx.x * 128;

    __shared__ alignas(16) short Xa[128 * 40];
    __shared__ alignas(16) short W1s[128 * 40];
    __shared__ alignas(16) short W3s[128 * 40];

    int tid = threadIdx.x;
    int sr = tid >> 1;
    int scb = (tid & 1) * 16;

    int lrA = bm + sr;
    int tok = (lrA < cnt) ? tok_list[base + lrA] : 0;
    const float* Arow  = X + (size_t)tok * HID_ + scb;
    const float* B1row = w1 + (size_t)e * INTER_ * HID_ + (size_t)(bn + sr) * HID_ + scb;
    const float* B3row = w3 + (size_t)e * INTER_ * HID_ + (size_t)(bn + sr) * HID_ + scb;
    short* XaW = Xa  + sr * 40 + scb;
    short* W1w = W1s + sr * 40 + scb;
    short* W3w = W3s + sr * 40 + scb;

    int wvid = tid >> 6, lane = tid & 63;
    int wm = (wvid >> 1) * 64, wn = (wvid & 1) * 64;
    int l15 = lane & 15, quad = lane >> 4;

    const short* XaR = Xa  + (wm + l15) * 40 + quad * 8;
    const short* W1r = W1s + (wn + l15) * 40 + quad * 8;
    const short* W3r = W3s + (wn + l15) * 40 + quad * 8;

    floatx4 acc1[4][4], acc3[4][4];
#pragma unroll
    for (int i = 0; i < 4; i++)
#pragma unroll
        for (int j = 0; j < 4; j++) { acc1[i][j] = (floatx4)0.f; acc3[i][j] = (floatx4)0.f; }

    for (int k0 = 0; k0 < HID_; k0 += 32) {
        float4 f0 = *(const float4*)(Arow + k0);
        float4 f1 = *(const float4*)(Arow + k0 + 4);
        float4 f2 = *(const float4*)(Arow + k0 + 8);
        float4 f3 = *(const float4*)(Arow + k0 + 12);
        float4 g0 = *(const float4*)(B1row + k0);
        float4 g1 = *(const float4*)(B1row + k0 + 4);
        float4 g2 = *(const float4*)(B1row + k0 + 8);
        float4 g3 = *(const float4*)(B1row + k0 + 12);
        float4 h0 = *(const float4*)(B3row + k0);
        float4 h1 = *(const float4*)(B3row + k0 + 4);
        float4 h2 = *(const float4*)(B3row + k0 + 8);
        float4 h3 = *(const float4*)(B3row + k0 + 12);
        cvt_store16(XaW, f0, f1, f2, f3);
        cvt_store16(W1w, g0, g1, g2, g3);
        cvt_store16(W3w, h0, h1, h2, h3);
        __syncthreads();

        short8 af[4], b1f[4], b3f[4];
#pragma unroll
        for (int i = 0; i < 4; i++) af[i] = *(const short8*)(XaR + i * 16 * 40);
#pragma unroll
        for (int j = 0; j < 4; j++) {
            b1f[j] = *(const short8*)(W1r + j * 16 * 40);
            b3f[j] = *(const short8*)(W3r + j * 16 * 40);
        }
#pragma unroll
        for (int i = 0; i < 4; i++)
#pragma unroll
            for (int j = 0; j < 4; j++) {
                acc1[i][j] = __builtin_amdgcn_mfma_f32_16x16x32_bf16(af[i], b1f[j], acc1[i][j], 0, 0, 0);
                acc3[i][j] = __builtin_amdgcn_mfma_f32_16x16x32_bf16(af[i], b3f[j], acc3[i][j], 0, 0, 0);
            }
        __syncthreads();
    }

#pragma unroll
    for (int i = 0; i < 4; i++) {
#pragma unroll
        for (int reg = 0; reg < 4; reg++) {
            int lrow = bm + wm + i * 16 + quad * 4 + reg;
            if (lrow >= cnt) continue;
            size_t rowoff = (size_t)(base + lrow) * INTER_;
#pragma unroll
            for (int j = 0; j < 4; j++) {
                float a = acc1[i][j][reg];
                float v = (a / (1.f + __expf(-a))) * acc3[i][j][reg];
                h13b[rowoff + bn + wn + j * 16 + l15] = __float2bfloat16(v);
            }
        }
    }
}

__global__ __launch_bounds__(256) void moe_gemm2_mfma(const __hip_bfloat16* __restrict__ h13b,
                                                      const float* __restrict__ w2,
                                                      const int* __restrict__ tok_list,
                                                      const float* __restrict__ wt_list,
                                                      const int* __restrict__ ebase,
                                                      const int* __restrict__ counts,
                                                      float* __restrict__ out) {
    int e = blockIdx.z;
    int cnt = counts[e];
    int bm = blockIdx.y * 128;
    if (bm >= cnt) return;
    int base = ebase[e];
    int bn = blockIdx.x * 128;

    __shared__ alignas(16) short Xa[128 * 40];
    __shared__ alignas(16) short Ws[128 * 40];

    int tid = threadIdx.x;
    int sr = tid >> 1;
    int scb = (tid & 1) * 16;

    int lrA = bm + sr;
    int slot = base + ((lrA < cnt) ? lrA : 0);
    const short* Arow = (const short*)h13b + (size_t)slot * INTER_ + scb;
    const float* Brow = w2 + (size_t)e * HID_ * INTER_ + (size_t)(bn + sr) * INTER_ + scb;
    short* XaW = Xa + sr * 40 + scb;
    short* WsW = Ws + sr * 40 + scb;

    int wvid = tid >> 6, lane = tid & 63;
    int wm = (wvid >> 1) * 64, wn = (wvid & 1) * 64;
    int l15 = lane & 15, quad = lane >> 4;

    const short* XaR = Xa + (wm + l15) * 40 + quad * 8;
    const short* WsR = Ws + (wn + l15) * 40 + quad * 8;

    floatx4 acc[4][4];
#pragma unroll
    for (int i = 0; i < 4; i++)
#pragma unroll
        for (int j = 0; j < 4; j++) acc[i][j] = (floatx4)0.f;

    for (int k0 = 0; k0 < INTER_; k0 += 32) {
        short8 v0 = *(const short8*)(Arow + k0);
        short8 v1 = *(const short8*)(Arow + k0 + 8);
        float4 g0 = *(const float4*)(Brow + k0);
        float4 g1 = *(const float4*)(Brow + k0 + 4);
        float4 g2 = *(const float4*)(Brow + k0 + 8);
        float4 g3 = *(const float4*)(Brow + k0 + 12);
        *(short8*)XaW = v0;
        *(short8*)(XaW + 8) = v1;
        cvt_store16(WsW, g0, g1, g2, g3);
        __syncthreads();

        short8 af[4], bf_[4];
#pragma unroll
        for (int i = 0; i < 4; i++) af[i] = *(const short8*)(XaR + i * 16 * 40);
#pragma unroll
        for (int j = 0; j < 4; j++) bf_[j] = *(const short8*)(WsR + j * 16 * 40);
#pragma unroll
        for (int i = 0; i < 4; i++)
#pragma unroll
            for (int j = 0; j < 4; j++)
                acc[i][j] = __builtin_amdgcn_mfma_f32_16x16x32_bf16(af[i], bf_[j], acc[i][j], 0, 0, 0);
        __syncthreads();
    }

#pragma unroll
    for (int i = 0; i < 4; i++) {
#pragma unroll
        for (int reg = 0; reg < 4; reg++) {
            int lrow = bm + wm + i * 16 + quad * 4 + reg;
            if (lrow >= cnt) continue;
            int tok = tok_list[base + lrow];
            float w = wt_list[base + lrow];
            size_t rowoff = (size_t)tok * HID_;
#pragma unroll
            for (int j = 0; j < 4; j++)
                atomicAdd(&out[rowoff + bn + wn + j * 16 + l15], w * acc[i][j][reg]);
        }
    }
}

__global__ void copy4_kernel(const float* __restrict__ src, float* __restrict__ dst, int n4) {
    int i = blockIdx.x * blockDim.x + threadIdx.x;
    if (i < n4) ((float4*)dst)[i] = ((const float4*)src)[i];
}

extern "C" void kernel_launch(void* const* d_in, const int* in_sizes, int n_in,
                              void* d_out, int out_size, void* d_ws, size_t ws_size,
                              hipStream_t stream) {
    const float* h      = (const float*)d_in[0];
    const int*   pos    = (const int*)d_in[1];
    const float* wq     = (const float*)d_in[2];
    const float* wk     = (const float*)d_in[3];
    const float* wv     = (const float*)d_in[4];
    const float* wo     = (const float*)d_in[5];
    const float* gate_w = (const float*)d_in[6];
    const float* w1     = (const float*)d_in[7];
    const float* w2     = (const float*)d_in[8];
    const float* w3     = (const float*)d_in[9];
    const float* ln1_w  = (const float*)d_in[10];
    const float* ln2_w  = (const float*)d_in[11];
    float* out = (float*)d_out;

    float* ws = (float*)d_ws;
    const size_t M1 = 1024 * 1024;
    float* xn1 = ws;                 // 2M floats (alias: ob)
    float* ob  = ws;
    float* qb  = ws + 2 * M1;        // 2M (alias: h2)
    float* h2  = ws + 2 * M1;
    float* kb  = ws + 4 * M1;        // 0.5M
    float* vb  = ws + 4 * M1 + M1 / 2; // 0.5M
    float* xn2 = ws + 5 * M1;        // 2M
    __hip_bfloat16* h13b = (__hip_bfloat16*)(ws + 7 * M1);  // 4096*3584 bf16
    float* smallf = ws + 14 * M1 + M1 / 2;
    int*   sel      = (int*)smallf;
    float* wtb      = smallf + 4096;
    int*   counts   = (int*)(smallf + 8192);
    int*   ebase    = (int*)(smallf + 8192 + 16);
    int*   cursor   = (int*)(smallf + 8192 + 32);
    int*   tok_list = (int*)(smallf + 8192 + 64);
    float* wt_list  = smallf + 8192 + 64 + 4352;

    // new-path bf16 staging buffers (beyond 15M floats)
    const size_t WELEM = (size_t)E_ * INTER_ * HID_;       // 29,360,128 bf16 elems per weight
    short* xn2b = (short*)(ws + 15 * M1);                  // T*HID bf16
    short* w1bb = (short*)(ws + 16 * M1);                  // WELEM bf16
    short* w3bb = w1bb + WELEM;                            // WELEM bf16
    short* w2bb = w1bb;                                    // reuse w1b slot after gemm13
    // attention bf16 buffers: alias w1bb region (used and consumed BEFORE cvt(w1) runs;
    // single stream => strictly ordered, safe)
    short* qbh = (short*)(ws + 16 * M1);                   // 2M shorts (1M floats)
    short* kbh = (short*)(ws + 17 * M1);                   // 0.5M shorts
    short* vbh = (short*)(ws + 17 * M1 + M1 / 4);          // 0.5M shorts
    const size_t need_bytes = (16 * M1 + WELEM) * sizeof(float);  // ~184.5 MB
    bool big = ws_size >= need_bytes;

    hipLaunchKernelGGL(init_counts_kernel, dim3(1), dim3(64), 0, stream, counts);
    hipLaunchKernelGGL(rmsnorm_kernel, dim3(T_), dim3(256), 0, stream, h, ln1_w, xn1);
    hipLaunchKernelGGL(gemm_f32, dim3(16, 32), dim3(256), 0, stream, xn1, wq, qb, (const float*)nullptr, T_, NH_ * HD_, HID_);
    hipLaunchKernelGGL(gemm_f32, dim3(4, 32),  dim3(256), 0, stream, xn1, wk, kb, (const float*)nullptr, T_, NKV_ * HD_, HID_);
    hipLaunchKernelGGL(gemm_f32, dim3(4, 32),  dim3(256), 0, stream, xn1, wv, vb, (const float*)nullptr, T_, NKV_ * HD_, HID_);
    {
        int tot = T_ * (NH_ + NKV_) * 32;
        hipLaunchKernelGGL(rope_kernel, dim3((tot + 255) / 256), dim3(256), 0, stream, qb, kb, pos);
    }
    if (big) {
        hipLaunchKernelGGL(cvt_bf16_kernel, dim3(1024), dim3(256), 0, stream, qb, qbh, T_ * NH_ * HD_ / 8);
        hipLaunchKernelGGL(cvt_bf16_kernel, dim3(256),  dim3(256), 0, stream, kb, kbh, T_ * NKV_ * HD_ / 8);
        hipLaunchKernelGGL(cvt_bf16_kernel, dim3(256),  dim3(256), 0, stream, vb, vbh, T_ * NKV_ * HD_ / 8);
        hipLaunchKernelGGL(flash_attn_mfma, dim3(32 * 16), dim3(256), 0, stream, qbh, kbh, vbh, ob);
    } else {
        hipLaunchKernelGGL(flash_attn_kernel, dim3(32 * 16), dim3(256), 0, stream, qb, kb, vb, ob);
    }
    hipLaunchKernelGGL(gemm_f32, dim3(16, 32), dim3(256), 0, stream, ob, wo, h2, h, T_, HID_, NH_ * HD_);
    hipLaunchKernelGGL(rmsnorm_kernel, dim3(T_), dim3(256), 0, stream, h2, ln2_w, xn2);
    hipLaunchKernelGGL(gating_kernel, dim3(T_), dim3(64), 0, stream, xn2, gate_w, sel, wtb, counts);
    hipLaunchKernelGGL(prefix_kernel, dim3(1), dim3(64), 0, stream, counts, ebase, cursor);
    hipLaunchKernelGGL(scatter_kernel, dim3((T_ + 255) / 256), dim3(256), 0, stream, sel, wtb, cursor, tok_list, wt_list);

    if (big) {
        const int n8w = (int)(WELEM / 8);
        hipLaunchKernelGGL(cvt_bf16_kernel, dim3(2048), dim3(256), 0, stream, w1, w1bb, n8w);
        hipLaunchKernelGGL(cvt_bf16_kernel, dim3(2048), dim3(256), 0, stream, w3, w3bb, n8w);
        hipLaunchKernelGGL(cvt_bf16_kernel, dim3(256),  dim3(256), 0, stream, xn2, xn2b, T_ * HID_ / 8);
        hipLaunchKernelGGL(moe_gemm13_v2, dim3(INTER_ / 128, 16, E_), dim3(256), 0, stream,
                           xn2b, w1bb, w3bb, tok_list, ebase, counts, h13b);
        hipLaunchKernelGGL(cvt_bf16_kernel, dim3(2048), dim3(256), 0, stream, w2, w2bb, n8w);
        hipLaunchKernelGGL(copy4_kernel, dim3((T_ * HID_ / 4 + 255) / 256), dim3(256), 0, stream, h2, out, T_ * HID_ / 4);
        hipLaunchKernelGGL(moe_gemm2_v2, dim3(HID_ / 128, 16, E_), dim3(256), 0, stream,
                           (const short*)h13b, w2bb, tok_list, wt_list, ebase, counts, out);
    } else {
        hipLaunchKernelGGL(moe_gemm13_mfma, dim3(INTER_ / 128, 16, E_), dim3(256), 0, stream,
                           xn2, w1, w3, tok_list, ebase, counts, h13b);
        hipLaunchKernelGGL(copy4_kernel, dim3((T_ * HID_ / 4 + 255) / 256), dim3(256), 0, stream, h2, out, T_ * HID_ / 4);
        hipLaunchKernelGGL(moe_gemm2_mfma, dim3(HID_ / 128, 16, E_), dim3(256), 0, stream,
                           h13b, w2, tok_list, wt_list, ebase, counts, out);
    }
}

// Round 4
// 892.279 us; speedup vs baseline: 1.9991x; 1.6166x over previous
//
#include <hip/hip_runtime.h>
#include <hip/hip_bf16.h>
#include <math.h>

#define T_    2048
#define HID_  1024
#define NH_   16
#define NKV_  4
#define HD_   64
#define E_    8
#define TOPK_ 2
#define INTER_ 3584
#define EPS_  1e-6f

typedef __attribute__((ext_vector_type(8))) short short8;
typedef __attribute__((ext_vector_type(4))) float floatx4;

__device__ inline short f2bf(float f) {
    __hip_bfloat16 b = __float2bfloat16(f);
    return *reinterpret_cast<short*>(&b);
}

__device__ inline void cvt_store16(short* dst, float4 a, float4 b, float4 c, float4 d) {
    short8 lo, hi;
    lo[0] = f2bf(a.x); lo[1] = f2bf(a.y); lo[2] = f2bf(a.z); lo[3] = f2bf(a.w);
    lo[4] = f2bf(b.x); lo[5] = f2bf(b.y); lo[6] = f2bf(b.z); lo[7] = f2bf(b.w);
    hi[0] = f2bf(c.x); hi[1] = f2bf(c.y); hi[2] = f2bf(c.z); hi[3] = f2bf(c.w);
    hi[4] = f2bf(d.x); hi[5] = f2bf(d.y); hi[6] = f2bf(d.z); hi[7] = f2bf(d.w);
    *(short8*)dst = lo;
    *(short8*)(dst + 8) = hi;
}

// async global->LDS, 16B per lane. LDS dest must be wave-uniform-base + lane*16.
__device__ inline void async_copy16(short* lds, const short* g) {
    __builtin_amdgcn_global_load_lds((const __attribute__((address_space(1))) void*)g,
                                     (__attribute__((address_space(3))) void*)lds, 16, 0, 0);
}

// ---------------- RMSNorm: one block (256 thr) per row ----------------
__global__ __launch_bounds__(256) void rmsnorm_kernel(const float* __restrict__ x,
                                                      const float* __restrict__ w,
                                                      float* __restrict__ o) {
    int t = blockIdx.x;
    const float* xr = x + (size_t)t * HID_;
    float s = 0.f;
    for (int d = threadIdx.x; d < HID_; d += 256) { float v = xr[d]; s += v * v; }
    __shared__ float red[256];
    red[threadIdx.x] = s; __syncthreads();
    for (int off = 128; off > 0; off >>= 1) {
        if (threadIdx.x < off) red[threadIdx.x] += red[threadIdx.x + off];
        __syncthreads();
    }
    float inv = rsqrtf(red[0] / (float)HID_ + EPS_);
    for (int d = threadIdx.x; d < HID_; d += 256)
        o[(size_t)t * HID_ + d] = w[d] * xr[d] * inv;
}

// ---------------- Generic fp32 GEMM (fallback path only) ----------------
__global__ __launch_bounds__(256) void gemm_f32(const float* __restrict__ A,
                                                const float* __restrict__ B,
                                                float* __restrict__ C,
                                                const float* __restrict__ addsrc,
                                                int M, int N, int K) {
    __shared__ float As[16][65];
    __shared__ float Bs[16][65];
    int tid = threadIdx.x;
    int tx = tid & 15, ty = tid >> 4;
    int bm = blockIdx.y * 64, bn = blockIdx.x * 64;
    float acc[4][4];
#pragma unroll
    for (int i = 0; i < 4; i++)
#pragma unroll
        for (int j = 0; j < 4; j++) acc[i][j] = 0.f;

    int mL[4], kL[4];
#pragma unroll
    for (int l = 0; l < 4; l++) { int idx = tid + l * 256; mL[l] = idx >> 4; kL[l] = idx & 15; }

    for (int k0 = 0; k0 < K; k0 += 16) {
#pragma unroll
        for (int l = 0; l < 4; l++) {
            int m = mL[l], kk = kL[l];
            int gr = bm + m;
            As[kk][m] = (gr < M) ? A[(size_t)gr * K + k0 + kk] : 0.f;
            int gc = bn + m;
            Bs[kk][m] = (gc < N) ? B[(size_t)gc * K + k0 + kk] : 0.f;
        }
        __syncthreads();
#pragma unroll
        for (int kk = 0; kk < 16; kk++) {
            float a[4], b[4];
#pragma unroll
            for (int i = 0; i < 4; i++) a[i] = As[kk][ty * 4 + i];
#pragma unroll
            for (int j = 0; j < 4; j++) b[j] = Bs[kk][tx * 4 + j];
#pragma unroll
            for (int i = 0; i < 4; i++)
#pragma unroll
                for (int j = 0; j < 4; j++) acc[i][j] += a[i] * b[j];
        }
        __syncthreads();
    }
#pragma unroll
    for (int i = 0; i < 4; i++) {
        int r = bm + ty * 4 + i;
        if (r >= M) continue;
#pragma unroll
        for (int j = 0; j < 4; j++) {
            int c = bn + tx * 4 + j;
            if (c >= N) continue;
            float v = acc[i][j];
            if (addsrc) v += addsrc[(size_t)r * N + c];
            C[(size_t)r * N + c] = v;
        }
    }
}

// ---------------- bf16 MFMA GEMM: C[M,N] = A[M,K] @ B[N,K]^T (+addsrc), fp32 out ----------------
// Requires M%128==0, N%128==0, K%32==0. Same verified pipeline as moe_gemm2_v2:
// 128x128 tile, BK=32, double-buffered linear LDS + global_load_lds(16B), 4 waves 4x4 mfma.
__global__ __launch_bounds__(256, 2) void gemm_bf16_v2(const short* __restrict__ A,
                                                       const short* __restrict__ B,
                                                       float* __restrict__ C,
                                                       const float* __restrict__ addsrc,
                                                       int M, int N, int K) {
    int bm = blockIdx.y * 128;
    int bn = blockIdx.x * 128;

    __shared__ alignas(16) short lds[2][2][128 * 32];  // 32 KiB

    int tid = threadIdx.x;
    int sr = tid >> 2;            // staging row 0..63 (and +64 second segment)
    int sc = (tid & 3) * 8;       // staging col
    int ldst = tid * 8;

    const short* aG0 = A + (size_t)(bm + sr) * K + sc;
    const short* aG1 = aG0 + (size_t)64 * K;
    const short* bG0 = B + (size_t)(bn + sr) * K + sc;
    const short* bG1 = bG0 + (size_t)64 * K;

    int wvid = tid >> 6, lane = tid & 63;
    int wm = (wvid >> 1) * 64, wn = (wvid & 1) * 64;
    int l15 = lane & 15, quad = lane >> 4;

    floatx4 acc[4][4];
#pragma unroll
    for (int i = 0; i < 4; i++)
#pragma unroll
        for (int j = 0; j < 4; j++) acc[i][j] = (floatx4)0.f;

#define STAGEG(b, k0) do {                                          \
        async_copy16(&lds[b][0][ldst],        aG0 + (k0));          \
        async_copy16(&lds[b][0][ldst + 2048], aG1 + (k0));          \
        async_copy16(&lds[b][1][ldst],        bG0 + (k0));          \
        async_copy16(&lds[b][1][ldst + 2048], bG1 + (k0));          \
    } while (0)

    STAGEG(0, 0);
    __syncthreads();

    int cur = 0;
    for (int k0 = 0; k0 < K; k0 += 32) {
        if (k0 + 32 < K) STAGEG(cur ^ 1, k0 + 32);

        const short* XaR = &lds[cur][0][(wm + l15) * 32 + quad * 8];
        const short* WsR = &lds[cur][1][(wn + l15) * 32 + quad * 8];
        short8 af[4], bf_[4];
#pragma unroll
        for (int i = 0; i < 4; i++) af[i] = *(const short8*)(XaR + i * 16 * 32);
#pragma unroll
        for (int j = 0; j < 4; j++) bf_[j] = *(const short8*)(WsR + j * 16 * 32);
#pragma unroll
        for (int i = 0; i < 4; i++)
#pragma unroll
            for (int j = 0; j < 4; j++)
                acc[i][j] = __builtin_amdgcn_mfma_f32_16x16x32_bf16(af[i], bf_[j], acc[i][j], 0, 0, 0);
        __syncthreads();
        cur ^= 1;
    }
#undef STAGEG

#pragma unroll
    for (int i = 0; i < 4; i++) {
#pragma unroll
        for (int reg = 0; reg < 4; reg++) {
            int r = bm + wm + i * 16 + quad * 4 + reg;
            size_t rowoff = (size_t)r * N;
#pragma unroll
            for (int j = 0; j < 4; j++) {
                int c = bn + wn + j * 16 + l15;
                float v = acc[i][j][reg];
                if (addsrc) v += addsrc[rowoff + c];
                C[rowoff + c] = v;
            }
        }
    }
}

// ---------------- RoPE in-place on q and k ----------------
__global__ void rope_kernel(float* __restrict__ qb, float* __restrict__ kb,
                            const int* __restrict__ pos_ids) {
    int idx = blockIdx.x * blockDim.x + threadIdx.x;
    const int totq = T_ * NH_ * 32;
    const int totk = T_ * NKV_ * 32;
    if (idx >= totq + totk) return;
    float* buf; int t, hh, i, hw;
    if (idx < totq) { buf = qb; hw = NH_;  t = idx / (NH_ * 32); int r = idx % (NH_ * 32); hh = r / 32; i = r % 32; }
    else { idx -= totq; buf = kb; hw = NKV_; t = idx / (NKV_ * 32); int r = idx % (NKV_ * 32); hh = r / 32; i = r % 32; }
    float pos = (float)pos_ids[t];
    float inv = expf(-(float)i * (13.815510558f / 32.0f));
    float fr = pos * inv;
    float c = cosf(fr), s = sinf(fr);
    size_t base = (size_t)t * hw * 64 + (size_t)hh * 64;
    float x1 = buf[base + i], x2 = buf[base + i + 32];
    buf[base + i]      = x1 * c - x2 * s;
    buf[base + i + 32] = x2 * c + x1 * s;
}

// ---------------- Flash attention v2: bf16 MFMA, bf16 output ----------------
__global__ __launch_bounds__(256) void flash_attn_mfma(const short* __restrict__ qbh,
                                                       const short* __restrict__ kbh,
                                                       const short* __restrict__ vbh,
                                                       short* __restrict__ obh) {
    __shared__ alignas(16) short Ks[64][80];
    __shared__ alignas(16) short Vt[64][80];
    __shared__ alignas(16) short Ps[64][80];

    int bid = blockIdx.x;
    int h = bid & 15;
    int qr = bid >> 4;
    int qt = (qr & 1) ? (31 - (qr >> 1)) : (qr >> 1);
    int q0 = qt * 64;
    int kvh = h >> 2;
    int tid = threadIdx.x;
    int w = tid >> 6, lane = tid & 63;
    int l15 = lane & 15, quad = lane >> 4;
    int str = tid >> 2, stc = tid & 3;

    short8 aq0, aq1;
    {
        const short* qrow = qbh + (size_t)(q0 + 16 * w + l15) * (NH_ * HD_) + h * HD_ + quad * 8;
        aq0 = *(const short8*)(qrow);
        aq1 = *(const short8*)(qrow + 32);
    }

    floatx4 o_acc[4];
    float m_i[4], l_i[4];
#pragma unroll
    for (int j = 0; j < 4; j++) o_acc[j] = (floatx4)0.f;
#pragma unroll
    for (int r = 0; r < 4; r++) { m_i[r] = -INFINITY; l_i[r] = 0.f; }

    int nt = q0 / 64 + 1;

    const short* kg = kbh + (size_t)str * (NKV_ * HD_) + kvh * HD_ + stc * 8;
    const short* vg = vbh + (size_t)str * (NKV_ * HD_) + kvh * HD_ + stc * 8;
    short8 kr0 = *(const short8*)kg;
    short8 kr1 = *(const short8*)(kg + 32);
    short8 vr0 = *(const short8*)vg;
    short8 vr1 = *(const short8*)(vg + 32);

    for (int it = 0; it < nt; ++it) {
        int t0 = it * 64;
        __syncthreads();
        *(short8*)&Ks[str][stc * 8]      = kr0;
        *(short8*)&Ks[str][32 + stc * 8] = kr1;
#pragma unroll
        for (int i = 0; i < 8; i++) {
            Vt[stc * 8 + i][str]      = vr0[i];
            Vt[32 + stc * 8 + i][str] = vr1[i];
        }
        if (it + 1 < nt) {
            const short* kgn = kbh + (size_t)(t0 + 64 + str) * (NKV_ * HD_) + kvh * HD_ + stc * 8;
            const short* vgn = vbh + (size_t)(t0 + 64 + str) * (NKV_ * HD_) + kvh * HD_ + stc * 8;
            kr0 = *(const short8*)kgn;
            kr1 = *(const short8*)(kgn + 32);
            vr0 = *(const short8*)vgn;
            vr1 = *(const short8*)(vgn + 32);
        }
        __syncthreads();

        floatx4 s[4];
#pragma unroll
        for (int j = 0; j < 4; j++) s[j] = (floatx4)0.f;
        __builtin_amdgcn_s_setprio(1);
#pragma unroll
        for (int j = 0; j < 4; j++) {
            short8 bk0 = *(const short8*)&Ks[16 * j + l15][quad * 8];
            short8 bk1 = *(const short8*)&Ks[16 * j + l15][32 + quad * 8];
            s[j] = __builtin_amdgcn_mfma_f32_16x16x32_bf16(aq0, bk0, s[j], 0, 0, 0);
            s[j] = __builtin_amdgcn_mfma_f32_16x16x32_bf16(aq1, bk1, s[j], 0, 0, 0);
        }
        __builtin_amdgcn_s_setprio(0);

        bool diag = (t0 == q0);
#pragma unroll
        for (int j = 0; j < 4; j++)
#pragma unroll
            for (int reg = 0; reg < 4; reg++) {
                s[j][reg] *= 0.125f;
                if (diag && (16 * j + l15 > 16 * w + quad * 4 + reg)) s[j][reg] = -INFINITY;
            }

#pragma unroll
        for (int reg = 0; reg < 4; reg++) {
            float mx = fmaxf(fmaxf(s[0][reg], s[1][reg]), fmaxf(s[2][reg], s[3][reg]));
#pragma unroll
            for (int off = 8; off >= 1; off >>= 1) mx = fmaxf(mx, __shfl_xor(mx, off));
            float mn = fmaxf(m_i[reg], mx);
            float alpha = __expf(m_i[reg] - mn);
            float rs = 0.f;
#pragma unroll
            for (int j = 0; j < 4; j++) { float p = __expf(s[j][reg] - mn); s[j][reg] = p; rs += p; }
#pragma unroll
            for (int off = 8; off >= 1; off >>= 1) rs += __shfl_xor(rs, off);
            l_i[reg] = l_i[reg] * alpha + rs;
            m_i[reg] = mn;
#pragma unroll
            for (int j = 0; j < 4; j++) o_acc[j][reg] *= alpha;
        }

#pragma unroll
        for (int j = 0; j < 4; j++)
#pragma unroll
            for (int reg = 0; reg < 4; reg++)
                Ps[16 * w + quad * 4 + reg][16 * j + l15] = f2bf(s[j][reg]);
        __asm__ volatile("s_waitcnt lgkmcnt(0)" ::: "memory");

        short8 ap0 = *(const short8*)&Ps[16 * w + l15][quad * 8];
        short8 ap1 = *(const short8*)&Ps[16 * w + l15][32 + quad * 8];
        __builtin_amdgcn_s_setprio(1);
#pragma unroll
        for (int j = 0; j < 4; j++) {
            short8 bv0 = *(const short8*)&Vt[16 * j + l15][quad * 8];
            short8 bv1 = *(const short8*)&Vt[16 * j + l15][32 + quad * 8];
            o_acc[j] = __builtin_amdgcn_mfma_f32_16x16x32_bf16(ap0, bv0, o_acc[j], 0, 0, 0);
            o_acc[j] = __builtin_amdgcn_mfma_f32_16x16x32_bf16(ap1, bv1, o_acc[j], 0, 0, 0);
        }
        __builtin_amdgcn_s_setprio(0);
    }

#pragma unroll
    for (int reg = 0; reg < 4; reg++) {
        float invl = 1.f / l_i[reg];
        size_t rbase = (size_t)(q0 + 16 * w + quad * 4 + reg) * (NH_ * HD_) + h * HD_;
#pragma unroll
        for (int j = 0; j < 4; j++)
            obh[rbase + 16 * j + l15] = f2bf(o_acc[j][reg] * invl);
    }
}

// ---------------- Flash attention (fp32 fallback) ----------------
__global__ __launch_bounds__(256) void flash_attn_kernel(const float* __restrict__ qb,
                                                         const float* __restrict__ kb,
                                                         const float* __restrict__ vb,
                                                         float* __restrict__ ob) {
    __shared__ float Qs[64][68];
    __shared__ float Ks[64][68];
    __shared__ float Vs[64][68];
    __shared__ float Ps[64][68];

    int bid = blockIdx.x;
    int h = bid & 15;
    int qr = bid >> 4;
    int qt = (qr & 1) ? (31 - (qr >> 1)) : (qr >> 1);
    int q0 = qt * 64;
    int kvh = h >> 2;
    int tid = threadIdx.x;
    int tx = tid & 15, ty = tid >> 4;

#pragma unroll
    for (int l = 0; l < 16; l++) {
        int idx = l * 256 + tid;
        int m = idx >> 6, d = idx & 63;
        Qs[d][m] = qb[(size_t)(q0 + m) * (NH_ * HD_) + h * HD_ + d];
    }

    float o_acc[4][4];
    float m_i[4], l_i[4];
#pragma unroll
    for (int i = 0; i < 4; i++) {
        m_i[i] = -INFINITY; l_i[i] = 0.f;
#pragma unroll
        for (int j = 0; j < 4; j++) o_acc[i][j] = 0.f;
    }

    for (int t0 = 0; t0 <= q0; t0 += 64) {
        __syncthreads();
#pragma unroll
        for (int l = 0; l < 16; l++) {
            int idx = l * 256 + tid;
            int m = idx >> 6, d = idx & 63;
            size_t g = (size_t)(t0 + m) * (NKV_ * HD_) + kvh * HD_ + d;
            Ks[d][m] = kb[g];
            Vs[m][d] = vb[g];
        }
        __syncthreads();

        float s[4][4];
#pragma unroll
        for (int i = 0; i < 4; i++)
#pragma unroll
            for (int j = 0; j < 4; j++) s[i][j] = 0.f;
#pragma unroll 4
        for (int kk = 0; kk < 64; kk++) {
            float4 a4 = *(const float4*)&Qs[kk][ty * 4];
            float4 b4 = *(const float4*)&Ks[kk][tx * 4];
            float a[4] = {a4.x, a4.y, a4.z, a4.w};
            float b[4] = {b4.x, b4.y, b4.z, b4.w};
#pragma unroll
            for (int i = 0; i < 4; i++)
#pragma unroll
                for (int j = 0; j < 4; j++) s[i][j] += a[i] * b[j];
        }

        bool diag = (t0 == q0);
#pragma unroll
        for (int i = 0; i < 4; i++) {
#pragma unroll
            for (int j = 0; j < 4; j++) {
                s[i][j] *= 0.125f;
                if (diag && (t0 + tx * 4 + j > q0 + ty * 4 + i)) s[i][j] = -INFINITY;
            }
        }

#pragma unroll
        for (int i = 0; i < 4; i++) {
            float mx = fmaxf(fmaxf(s[i][0], s[i][1]), fmaxf(s[i][2], s[i][3]));
#pragma unroll
            for (int off = 8; off >= 1; off >>= 1) mx = fmaxf(mx, __shfl_xor(mx, off));
            float mn = fmaxf(m_i[i], mx);
            float alpha = __expf(m_i[i] - mn);
            float rs = 0.f;
#pragma unroll
            for (int j = 0; j < 4; j++) { float p = __expf(s[i][j] - mn); s[i][j] = p; rs += p; }
#pragma unroll
            for (int off = 8; off >= 1; off >>= 1) rs += __shfl_xor(rs, off);
            l_i[i] = l_i[i] * alpha + rs;
            m_i[i] = mn;
#pragma unroll
            for (int j = 0; j < 4; j++) o_acc[i][j] *= alpha;
        }

#pragma unroll
        for (int j = 0; j < 4; j++)
#pragma unroll
            for (int i = 0; i < 4; i++)
                Ps[tx * 4 + j][ty * 4 + i] = s[i][j];
        __syncthreads();

#pragma unroll 4
        for (int kk = 0; kk < 64; kk++) {
            float4 a4 = *(const float4*)&Ps[kk][ty * 4];
            float4 b4 = *(const float4*)&Vs[kk][tx * 4];
            float a[4] = {a4.x, a4.y, a4.z, a4.w};
            float b[4] = {b4.x, b4.y, b4.z, b4.w};
#pragma unroll
            for (int i = 0; i < 4; i++)
#pragma unroll
                for (int j = 0; j < 4; j++) o_acc[i][j] += a[i] * b[j];
        }
    }

#pragma unroll
    for (int i = 0; i < 4; i++) {
        float invl = 1.f / l_i[i];
        int r = q0 + ty * 4 + i;
#pragma unroll
        for (int j = 0; j < 4; j++)
            ob[(size_t)r * (NH_ * HD_) + h * HD_ + tx * 4 + j] = o_acc[i][j] * invl;
    }
}

// ---------------- Gating: one wave per token ----------------
__global__ __launch_bounds__(64) void gating_kernel(const float* __restrict__ xn2,
                                                    const float* __restrict__ gate_w,
                                                    int* __restrict__ sel,
                                                    float* __restrict__ wt,
                                                    int* __restrict__ counts) {
    int t = blockIdx.x, lane = threadIdx.x;
    const float* x = xn2 + (size_t)t * HID_;
    float logits[E_];
    for (int e = 0; e < E_; e++) {
        float p = 0.f;
        for (int d = lane; d < HID_; d += 64) p += x[d] * gate_w[(size_t)e * HID_ + d];
#pragma unroll
        for (int off = 32; off > 0; off >>= 1) p += __shfl_xor(p, off);
        logits[e] = p;
    }
    float mx = logits[0];
    for (int e = 1; e < E_; e++) mx = fmaxf(mx, logits[e]);
    float pr[E_]; float sum = 0.f;
    for (int e = 0; e < E_; e++) { pr[e] = __expf(logits[e] - mx); sum += pr[e]; }
    int e1 = 0; float p1 = pr[0];
    for (int e = 1; e < E_; e++) if (pr[e] > p1) { p1 = pr[e]; e1 = e; }
    int e2 = -1; float p2 = -1.f;
    for (int e = 0; e < E_; e++) if (e != e1 && pr[e] > p2) { p2 = pr[e]; e2 = e; }
    if (lane == 0) {
        float denom = p1 + p2;
        sel[t * 2] = e1; sel[t * 2 + 1] = e2;
        wt[t * 2] = p1 / denom; wt[t * 2 + 1] = p2 / denom;
        atomicAdd(&counts[e1], 1);
        atomicAdd(&counts[e2], 1);
    }
}

__global__ void init_counts_kernel(int* counts) {
    if (threadIdx.x < E_) counts[threadIdx.x] = 0;
}

__global__ void prefix_kernel(const int* __restrict__ counts, int* __restrict__ ebase,
                              int* __restrict__ cursor) {
    if (threadIdx.x == 0) {
        int b = 0;
        for (int e = 0; e < E_; e++) { ebase[e] = b; cursor[e] = b; b += counts[e]; }
    }
}

__global__ void scatter_kernel(const int* __restrict__ sel, const float* __restrict__ wt,
                               int* __restrict__ cursor, int* __restrict__ tok_list,
                               float* __restrict__ wt_list) {
    int t = blockIdx.x * blockDim.x + threadIdx.x;
    if (t >= T_) return;
    for (int j = 0; j < 2; j++) {
        int e = sel[t * 2 + j];
        float w = wt[t * 2 + j];
        int p = atomicAdd(&cursor[e], 1);
        tok_list[p] = t;
        wt_list[p] = w;
    }
}

// ---------------- fp32 -> bf16 bulk convert (RNE, memory-bound) ----------------
__global__ __launch_bounds__(256) void cvt_bf16_kernel(const float* __restrict__ src,
                                                       short* __restrict__ dst, int n8) {
    int stride = gridDim.x * blockDim.x;
    for (int i = blockIdx.x * blockDim.x + threadIdx.x; i < n8; i += stride) {
        float4 a = ((const float4*)src)[2 * i];
        float4 b = ((const float4*)src)[2 * i + 1];
        short8 o;
        o[0] = f2bf(a.x); o[1] = f2bf(a.y); o[2] = f2bf(a.z); o[3] = f2bf(a.w);
        o[4] = f2bf(b.x); o[5] = f2bf(b.y); o[6] = f2bf(b.z); o[7] = f2bf(b.w);
        ((short8*)dst)[i] = o;
    }
}

// ---------------- MoE GEMM 1&3 v2 ----------------
__global__ __launch_bounds__(256, 2) void moe_gemm13_v2(const short* __restrict__ Xb,
                                                        const short* __restrict__ w1b,
                                                        const short* __restrict__ w3b,
                                                        const int* __restrict__ tok_list,
                                                        const int* __restrict__ ebase,
                                                        const int* __restrict__ counts,
                                                        __hip_bfloat16* __restrict__ h13b) {
    int e = blockIdx.z;
    int cnt = counts[e];
    int bm = blockIdx.y * 128;
    if (cnt <= 0 || bm >= cnt) return;
    int base = ebase[e];
    int bn = blockIdx.x * 128;

    __shared__ alignas(16) short lds[2][3][128 * 32];  // 48 KiB

    int tid = threadIdx.x;
    int sr = tid >> 2;
    int sc = (tid & 3) * 8;
    int ldst = tid * 8;

    int lr0 = bm + sr, lr1 = bm + sr + 64;
    int tok0 = tok_list[base + (lr0 < cnt ? lr0 : cnt - 1)];
    int tok1 = tok_list[base + (lr1 < cnt ? lr1 : cnt - 1)];
    const short* aG0 = Xb + (size_t)tok0 * HID_ + sc;
    const short* aG1 = Xb + (size_t)tok1 * HID_ + sc;
    const short* b1G0 = w1b + (size_t)e * INTER_ * HID_ + (size_t)(bn + sr) * HID_ + sc;
    const short* b1G1 = b1G0 + (size_t)64 * HID_;
    const short* b3G0 = w3b + (size_t)e * INTER_ * HID_ + (size_t)(bn + sr) * HID_ + sc;
    const short* b3G1 = b3G0 + (size_t)64 * HID_;

    int wvid = tid >> 6, lane = tid & 63;
    int wm = (wvid >> 1) * 64, wn = (wvid & 1) * 64;
    int l15 = lane & 15, quad = lane >> 4;

    floatx4 acc1[4][4], acc3[4][4];
#pragma unroll
    for (int i = 0; i < 4; i++)
#pragma unroll
        for (int j = 0; j < 4; j++) { acc1[i][j] = (floatx4)0.f; acc3[i][j] = (floatx4)0.f; }

#define STAGE13(b, k0) do {                                          \
        async_copy16(&lds[b][0][ldst],        aG0 + (k0));           \
        async_copy16(&lds[b][0][ldst + 2048], aG1 + (k0));           \
        async_copy16(&lds[b][1][ldst],        b1G0 + (k0));          \
        async_copy16(&lds[b][1][ldst + 2048], b1G1 + (k0));          \
        async_copy16(&lds[b][2][ldst],        b3G0 + (k0));          \
        async_copy16(&lds[b][2][ldst + 2048], b3G1 + (k0));          \
    } while (0)

    STAGE13(0, 0);
    __syncthreads();

    int cur = 0;
    for (int k0 = 0; k0 < HID_; k0 += 32) {
        if (k0 + 32 < HID_) STAGE13(cur ^ 1, k0 + 32);

        const short* XaR = &lds[cur][0][(wm + l15) * 32 + quad * 8];
        const short* W1r = &lds[cur][1][(wn + l15) * 32 + quad * 8];
        const short* W3r = &lds[cur][2][(wn + l15) * 32 + quad * 8];
        short8 af[4], b1f[4], b3f[4];
#pragma unroll
        for (int i = 0; i < 4; i++) af[i] = *(const short8*)(XaR + i * 16 * 32);
#pragma unroll
        for (int j = 0; j < 4; j++) {
            b1f[j] = *(const short8*)(W1r + j * 16 * 32);
            b3f[j] = *(const short8*)(W3r + j * 16 * 32);
        }
#pragma unroll
        for (int i = 0; i < 4; i++)
#pragma unroll
            for (int j = 0; j < 4; j++) {
                acc1[i][j] = __builtin_amdgcn_mfma_f32_16x16x32_bf16(af[i], b1f[j], acc1[i][j], 0, 0, 0);
                acc3[i][j] = __builtin_amdgcn_mfma_f32_16x16x32_bf16(af[i], b3f[j], acc3[i][j], 0, 0, 0);
            }
        __syncthreads();
        cur ^= 1;
    }
#undef STAGE13

#pragma unroll
    for (int i = 0; i < 4; i++) {
#pragma unroll
        for (int reg = 0; reg < 4; reg++) {
            int lrow = bm + wm + i * 16 + quad * 4 + reg;
            if (lrow >= cnt) continue;
            size_t rowoff = (size_t)(base + lrow) * INTER_;
#pragma unroll
            for (int j = 0; j < 4; j++) {
                float a = acc1[i][j][reg];
                float v = (a / (1.f + __expf(-a))) * acc3[i][j][reg];
                h13b[rowoff + bn + wn + j * 16 + l15] = __float2bfloat16(v);
            }
        }
    }
}

// ---------------- MoE GEMM 2 v2 ----------------
__global__ __launch_bounds__(256, 2) void moe_gemm2_v2(const short* __restrict__ h13s,
                                                       const short* __restrict__ w2b,
                                                       const int* __restrict__ tok_list,
                                                       const float* __restrict__ wt_list,
                                                       const int* __restrict__ ebase,
                                                       const int* __restrict__ counts,
                                                       float* __restrict__ out) {
    int e = blockIdx.z;
    int cnt = counts[e];
    int bm = blockIdx.y * 128;
    if (cnt <= 0 || bm >= cnt) return;
    int base = ebase[e];
    int bn = blockIdx.x * 128;

    __shared__ alignas(16) short lds[2][2][128 * 32];  // 32 KiB

    int tid = threadIdx.x;
    int sr = tid >> 2;
    int sc = (tid & 3) * 8;
    int ldst = tid * 8;

    int lr0 = bm + sr, lr1 = bm + sr + 64;
    int slot0 = base + (lr0 < cnt ? lr0 : cnt - 1);
    int slot1 = base + (lr1 < cnt ? lr1 : cnt - 1);
    const short* aG0 = h13s + (size_t)slot0 * INTER_ + sc;
    const short* aG1 = h13s + (size_t)slot1 * INTER_ + sc;
    const short* bG0 = w2b + (size_t)e * HID_ * INTER_ + (size_t)(bn + sr) * INTER_ + sc;
    const short* bG1 = bG0 + (size_t)64 * INTER_;

    int wvid = tid >> 6, lane = tid & 63;
    int wm = (wvid >> 1) * 64, wn = (wvid & 1) * 64;
    int l15 = lane & 15, quad = lane >> 4;

    floatx4 acc[4][4];
#pragma unroll
    for (int i = 0; i < 4; i++)
#pragma unroll
        for (int j = 0; j < 4; j++) acc[i][j] = (floatx4)0.f;

#define STAGE2(b, k0) do {                                          \
        async_copy16(&lds[b][0][ldst],        aG0 + (k0));          \
        async_copy16(&lds[b][0][ldst + 2048], aG1 + (k0));          \
        async_copy16(&lds[b][1][ldst],        bG0 + (k0));          \
        async_copy16(&lds[b][1][ldst + 2048], bG1 + (k0));          \
    } while (0)

    STAGE2(0, 0);
    __syncthreads();

    int cur = 0;
    for (int k0 = 0; k0 < INTER_; k0 += 32) {
        if (k0 + 32 < INTER_) STAGE2(cur ^ 1, k0 + 32);

        const short* XaR = &lds[cur][0][(wm + l15) * 32 + quad * 8];
        const short* WsR = &lds[cur][1][(wn + l15) * 32 + quad * 8];
        short8 af[4], bf_[4];
#pragma unroll
        for (int i = 0; i < 4; i++) af[i] = *(const short8*)(XaR + i * 16 * 32);
#pragma unroll
        for (int j = 0; j < 4; j++) bf_[j] = *(const short8*)(WsR + j * 16 * 32);
#pragma unroll
        for (int i = 0; i < 4; i++)
#pragma unroll
            for (int j = 0; j < 4; j++)
                acc[i][j] = __builtin_amdgcn_mfma_f32_16x16x32_bf16(af[i], bf_[j], acc[i][j], 0, 0, 0);
        __syncthreads();
        cur ^= 1;
    }
#undef STAGE2

#pragma unroll
    for (int i = 0; i < 4; i++) {
#pragma unroll
        for (int reg = 0; reg < 4; reg++) {
            int lrow = bm + wm + i * 16 + quad * 4 + reg;
            if (lrow >= cnt) continue;
            int tok = tok_list[base + lrow];
            float w = wt_list[base + lrow];
            size_t rowoff = (size_t)tok * HID_;
#pragma unroll
            for (int j = 0; j < 4; j++)
                atomicAdd(&out[rowoff + bn + wn + j * 16 + l15], w * acc[i][j][reg]);
        }
    }
}

// ---------------- Fallback (old) MoE kernels ----------------
__global__ __launch_bounds__(256) void moe_gemm13_mfma(const float* __restrict__ X,
                                                       const float* __restrict__ w1,
                                                       const float* __restrict__ w3,
                                                       const int* __restrict__ tok_list,
                                                       const int* __restrict__ ebase,
                                                       const int* __restrict__ counts,
                                                       __hip_bfloat16* __restrict__ h13b) {
    int e = blockIdx.z;
    int cnt = counts[e];
    int bm = blockIdx.y * 128;
    if (bm >= cnt) return;
    int base = ebase[e];
    int bn = blockIdx.x * 128;

    __shared__ alignas(16) short Xa[128 * 40];
    __shared__ alignas(16) short W1s[128 * 40];
    __shared__ alignas(16) short W3s[128 * 40];

    int tid = threadIdx.x;
    int sr = tid >> 1;
    int scb = (tid & 1) * 16;

    int lrA = bm + sr;
    int tok = (lrA < cnt) ? tok_list[base + lrA] : 0;
    const float* Arow  = X + (size_t)tok * HID_ + scb;
    const float* B1row = w1 + (size_t)e * INTER_ * HID_ + (size_t)(bn + sr) * HID_ + scb;
    const float* B3row = w3 + (size_t)e * INTER_ * HID_ + (size_t)(bn + sr) * HID_ + scb;
    short* XaW = Xa  + sr * 40 + scb;
    short* W1w = W1s + sr * 40 + scb;
    short* W3w = W3s + sr * 40 + scb;

    int wvid = tid >> 6, lane = tid & 63;
    int wm = (wvid >> 1) * 64, wn = (wvid & 1) * 64;
    int l15 = lane & 15, quad = lane >> 4;

    const short* XaR = Xa  + (wm + l15) * 40 + quad * 8;
    const short* W1r = W1s + (wn + l15) * 40 + quad * 8;
    const short* W3r = W3s + (wn + l15) * 40 + quad * 8;

    floatx4 acc1[4][4], acc3[4][4];
#pragma unroll
    for (int i = 0; i < 4; i++)
#pragma unroll
        for (int j = 0; j < 4; j++) { acc1[i][j] = (floatx4)0.f; acc3[i][j] = (floatx4)0.f; }

    for (int k0 = 0; k0 < HID_; k0 += 32) {
        float4 f0 = *(const float4*)(Arow + k0);
        float4 f1 = *(const float4*)(Arow + k0 + 4);
        float4 f2 = *(const float4*)(Arow + k0 + 8);
        float4 f3 = *(const float4*)(Arow + k0 + 12);
        float4 g0 = *(const float4*)(B1row + k0);
        float4 g1 = *(const float4*)(B1row + k0 + 4);
        float4 g2 = *(const float4*)(B1row + k0 + 8);
        float4 g3 = *(const float4*)(B1row + k0 + 12);
        float4 h0 = *(const float4*)(B3row + k0);
        float4 h1 = *(const float4*)(B3row + k0 + 4);
        float4 h2 = *(const float4*)(B3row + k0 + 8);
        float4 h3 = *(const float4*)(B3row + k0 + 12);
        cvt_store16(XaW, f0, f1, f2, f3);
        cvt_store16(W1w, g0, g1, g2, g3);
        cvt_store16(W3w, h0, h1, h2, h3);
        __syncthreads();

        short8 af[4], b1f[4], b3f[4];
#pragma unroll
        for (int i = 0; i < 4; i++) af[i] = *(const short8*)(XaR + i * 16 * 40);
#pragma unroll
        for (int j = 0; j < 4; j++) {
            b1f[j] = *(const short8*)(W1r + j * 16 * 40);
            b3f[j] = *(const short8*)(W3r + j * 16 * 40);
        }
#pragma unroll
        for (int i = 0; i < 4; i++)
#pragma unroll
            for (int j = 0; j < 4; j++) {
                acc1[i][j] = __builtin_amdgcn_mfma_f32_16x16x32_bf16(af[i], b1f[j], acc1[i][j], 0, 0, 0);
                acc3[i][j] = __builtin_amdgcn_mfma_f32_16x16x32_bf16(af[i], b3f[j], acc3[i][j], 0, 0, 0);
            }
        __syncthreads();
    }

#pragma unroll
    for (int i = 0; i < 4; i++) {
#pragma unroll
        for (int reg = 0; reg < 4; reg++) {
            int lrow = bm + wm + i * 16 + quad * 4 + reg;
            if (lrow >= cnt) continue;
            size_t rowoff = (size_t)(base + lrow) * INTER_;
#pragma unroll
            for (int j = 0; j < 4; j++) {
                float a = acc1[i][j][reg];
                float v = (a / (1.f + __expf(-a))) * acc3[i][j][reg];
                h13b[rowoff + bn + wn + j * 16 + l15] = __float2bfloat16(v);
            }
        }
    }
}

__global__ __launch_bounds__(256) void moe_gemm2_mfma(const __hip_bfloat16* __restrict__ h13b,
                                                      const float* __restrict__ w2,
                                                      const int* __restrict__ tok_list,
                                                      const float* __restrict__ wt_list,
                                                      const int* __restrict__ ebase,
                                                      const int* __restrict__ counts,
                                                      float* __restrict__ out) {
    int e = blockIdx.z;
    int cnt = counts[e];
    int bm = blockIdx.y * 128;
    if (bm >= cnt) return;
    int base = ebase[e];
    int bn = blockIdx.x * 128;

    __shared__ alignas(16) short Xa[128 * 40];
    __shared__ alignas(16) short Ws[128 * 40];

    int tid = threadIdx.x;
    int sr = tid >> 1;
    int scb = (tid & 1) * 16;

    int lrA = bm + sr;
    int slot = base + ((lrA < cnt) ? lrA : 0);
    const short* Arow = (const short*)h13b + (size_t)slot * INTER_ + scb;
    const float* Brow = w2 + (size_t)e * HID_ * INTER_ + (size_t)(bn + sr) * INTER_ + scb;
    short* XaW = Xa + sr * 40 + scb;
    short* WsW = Ws + sr * 40 + scb;

    int wvid = tid >> 6, lane = tid & 63;
    int wm = (wvid >> 1) * 64, wn = (wvid & 1) * 64;
    int l15 = lane & 15, quad = lane >> 4;

    const short* XaR = Xa + (wm + l15) * 40 + quad * 8;
    const short* WsR = Ws + (wn + l15) * 40 + quad * 8;

    floatx4 acc[4][4];
#pragma unroll
    for (int i = 0; i < 4; i++)
#pragma unroll
        for (int j = 0; j < 4; j++) acc[i][j] = (floatx4)0.f;

    for (int k0 = 0; k0 < INTER_; k0 += 32) {
        short8 v0 = *(const short8*)(Arow + k0);
        short8 v1 = *(const short8*)(Arow + k0 + 8);
        float4 g0 = *(const float4*)(Brow + k0);
        float4 g1 = *(const float4*)(Brow + k0 + 4);
        float4 g2 = *(const float4*)(Brow + k0 + 8);
        float4 g3 = *(const float4*)(Brow + k0 + 12);
        *(short8*)XaW = v0;
        *(short8*)(XaW + 8) = v1;
        cvt_store16(WsW, g0, g1, g2, g3);
        __syncthreads();

        short8 af[4], bf_[4];
#pragma unroll
        for (int i = 0; i < 4; i++) af[i] = *(const short8*)(XaR + i * 16 * 40);
#pragma unroll
        for (int j = 0; j < 4; j++) bf_[j] = *(const short8*)(WsR + j * 16 * 40);
#pragma unroll
        for (int i = 0; i < 4; i++)
#pragma unroll
            for (int j = 0; j < 4; j++)
                acc[i][j] = __builtin_amdgcn_mfma_f32_16x16x32_bf16(af[i], bf_[j], acc[i][j], 0, 0, 0);
        __syncthreads();
    }

#pragma unroll
    for (int i = 0; i < 4; i++) {
#pragma unroll
        for (int reg = 0; reg < 4; reg++) {
            int lrow = bm + wm + i * 16 + quad * 4 + reg;
            if (lrow >= cnt) continue;
            int tok = tok_list[base + lrow];
            float w = wt_list[base + lrow];
            size_t rowoff = (size_t)tok * HID_;
#pragma unroll
            for (int j = 0; j < 4; j++)
                atomicAdd(&out[rowoff + bn + wn + j * 16 + l15], w * acc[i][j][reg]);
        }
    }
}

__global__ void copy4_kernel(const float* __restrict__ src, float* __restrict__ dst, int n4) {
    int i = blockIdx.x * blockDim.x + threadIdx.x;
    if (i < n4) ((float4*)dst)[i] = ((const float4*)src)[i];
}

extern "C" void kernel_launch(void* const* d_in, const int* in_sizes, int n_in,
                              void* d_out, int out_size, void* d_ws, size_t ws_size,
                              hipStream_t stream) {
    const float* h      = (const float*)d_in[0];
    const int*   pos    = (const int*)d_in[1];
    const float* wq     = (const float*)d_in[2];
    const float* wk     = (const float*)d_in[3];
    const float* wv     = (const float*)d_in[4];
    const float* wo     = (const float*)d_in[5];
    const float* gate_w = (const float*)d_in[6];
    const float* w1     = (const float*)d_in[7];
    const float* w2     = (const float*)d_in[8];
    const float* w3     = (const float*)d_in[9];
    const float* ln1_w  = (const float*)d_in[10];
    const float* ln2_w  = (const float*)d_in[11];
    float* out = (float*)d_out;

    float* ws = (float*)d_ws;
    const size_t M1 = 1024 * 1024;
    float* xn1 = ws;                 // 2M floats (alias: ob)
    float* ob  = ws;
    float* qb  = ws + 2 * M1;        // 2M (alias: h2)
    float* h2  = ws + 2 * M1;
    float* kb  = ws + 4 * M1;        // 0.5M
    float* vb  = ws + 4 * M1 + M1 / 2; // 0.5M
    float* xn2 = ws + 5 * M1;        // 2M
    __hip_bfloat16* h13b = (__hip_bfloat16*)(ws + 7 * M1);  // ends at 14.34M floats
    float* smallf = ws + 14 * M1 + M1 / 2;
    int*   sel      = (int*)smallf;
    float* wtb      = smallf + 4096;
    int*   counts   = (int*)(smallf + 8192);
    int*   ebase    = (int*)(smallf + 8192 + 16);
    int*   cursor   = (int*)(smallf + 8192 + 32);
    int*   tok_list = (int*)(smallf + 8192 + 64);
    float* wt_list  = smallf + 8192 + 64 + 4352;

    // new-path bf16 staging buffers (beyond 15M floats)
    const size_t WELEM = (size_t)E_ * INTER_ * HID_;       // 29,360,128 bf16 elems per weight
    short* xn2b = (short*)(ws + 15 * M1);                  // T*HID bf16
    short* w1bb = (short*)(ws + 16 * M1);                  // WELEM bf16
    short* w3bb = w1bb + WELEM;                            // WELEM bf16
    short* w2bb = w1bb;                                    // reuse w1b slot after gemm13
    // attention + projection bf16 buffers: alias w1bb region (all consumed BEFORE
    // cvt(w1) runs; single stream => strictly ordered, safe)
    short* qbh  = (short*)(ws + 16 * M1);                  // 2M shorts
    short* kbh  = (short*)(ws + 17 * M1);                  // 0.5M shorts
    short* vbh  = (short*)(ws + 17 * M1 + M1 / 4);         // 0.5M shorts
    short* wqb  = (short*)(ws + 17 * M1 + M1 / 2);         // 1M shorts (1024x1024)
    short* wkb  = (short*)(ws + 18 * M1);                  // 0.25M shorts
    short* wvb  = (short*)(ws + 18 * M1 + M1 / 8);         // 0.25M shorts
    short* wob  = (short*)(ws + 18 * M1 + M1 / 4);         // 1M shorts
    short* xn1b = (short*)(ws + 18 * M1 + 3 * M1 / 4);     // 2M shorts
    short* obh  = (short*)(ws + 19 * M1 + 3 * M1 / 4);     // 2M shorts -> ends 20.75M floats
    const size_t need_bytes = (16 * M1 + WELEM) * sizeof(float);  // ~184.5 MB
    bool big = ws_size >= need_bytes;

    hipLaunchKernelGGL(init_counts_kernel, dim3(1), dim3(64), 0, stream, counts);
    hipLaunchKernelGGL(rmsnorm_kernel, dim3(T_), dim3(256), 0, stream, h, ln1_w, xn1);

    if (big) {
        // bf16 projection path: cvt weights + activations, MFMA GEMMs
        hipLaunchKernelGGL(cvt_bf16_kernel, dim3(512), dim3(256), 0, stream, wq, wqb, NH_ * HD_ * HID_ / 8);
        hipLaunchKernelGGL(cvt_bf16_kernel, dim3(128), dim3(256), 0, stream, wk, wkb, NKV_ * HD_ * HID_ / 8);
        hipLaunchKernelGGL(cvt_bf16_kernel, dim3(128), dim3(256), 0, stream, wv, wvb, NKV_ * HD_ * HID_ / 8);
        hipLaunchKernelGGL(cvt_bf16_kernel, dim3(512), dim3(256), 0, stream, wo, wob, HID_ * NH_ * HD_ / 8);
        hipLaunchKernelGGL(cvt_bf16_kernel, dim3(1024), dim3(256), 0, stream, xn1, xn1b, T_ * HID_ / 8);
        hipLaunchKernelGGL(gemm_bf16_v2, dim3(NH_ * HD_ / 128, T_ / 128), dim3(256), 0, stream,
                           xn1b, wqb, qb, (const float*)nullptr, T_, NH_ * HD_, HID_);
        hipLaunchKernelGGL(gemm_bf16_v2, dim3(NKV_ * HD_ / 128, T_ / 128), dim3(256), 0, stream,
                           xn1b, wkb, kb, (const float*)nullptr, T_, NKV_ * HD_, HID_);
        hipLaunchKernelGGL(gemm_bf16_v2, dim3(NKV_ * HD_ / 128, T_ / 128), dim3(256), 0, stream,
                           xn1b, wvb, vb, (const float*)nullptr, T_, NKV_ * HD_, HID_);
        {
            int tot = T_ * (NH_ + NKV_) * 32;
            hipLaunchKernelGGL(rope_kernel, dim3((tot + 255) / 256), dim3(256), 0, stream, qb, kb, pos);
        }
        hipLaunchKernelGGL(cvt_bf16_kernel, dim3(1024), dim3(256), 0, stream, qb, qbh, T_ * NH_ * HD_ / 8);
        hipLaunchKernelGGL(cvt_bf16_kernel, dim3(256),  dim3(256), 0, stream, kb, kbh, T_ * NKV_ * HD_ / 8);
        hipLaunchKernelGGL(cvt_bf16_kernel, dim3(256),  dim3(256), 0, stream, vb, vbh, T_ * NKV_ * HD_ / 8);
        hipLaunchKernelGGL(flash_attn_mfma, dim3(32 * 16), dim3(256), 0, stream, qbh, kbh, vbh, obh);
        hipLaunchKernelGGL(gemm_bf16_v2, dim3(HID_ / 128, T_ / 128), dim3(256), 0, stream,
                           obh, wob, h2, h, T_, HID_, NH_ * HD_);
    } else {
        hipLaunchKernelGGL(gemm_f32, dim3(16, 32), dim3(256), 0, stream, xn1, wq, qb, (const float*)nullptr, T_, NH_ * HD_, HID_);
        hipLaunchKernelGGL(gemm_f32, dim3(4, 32),  dim3(256), 0, stream, xn1, wk, kb, (const float*)nullptr, T_, NKV_ * HD_, HID_);
        hipLaunchKernelGGL(gemm_f32, dim3(4, 32),  dim3(256), 0, stream, xn1, wv, vb, (const float*)nullptr, T_, NKV_ * HD_, HID_);
        {
            int tot = T_ * (NH_ + NKV_) * 32;
            hipLaunchKernelGGL(rope_kernel, dim3((tot + 255) / 256), dim3(256), 0, stream, qb, kb, pos);
        }
        hipLaunchKernelGGL(flash_attn_kernel, dim3(32 * 16), dim3(256), 0, stream, qb, kb, vb, ob);
        hipLaunchKernelGGL(gemm_f32, dim3(16, 32), dim3(256), 0, stream, ob, wo, h2, h, T_, HID_, NH_ * HD_);
    }

    hipLaunchKernelGGL(rmsnorm_kernel, dim3(T_), dim3(256), 0, stream, h2, ln2_w, xn2);
    hipLaunchKernelGGL(gating_kernel, dim3(T_), dim3(64), 0, stream, xn2, gate_w, sel, wtb, counts);
    hipLaunchKernelGGL(prefix_kernel, dim3(1), dim3(64), 0, stream, counts, ebase, cursor);
    hipLaunchKernelGGL(scatter_kernel, dim3((T_ + 255) / 256), dim3(256), 0, stream, sel, wtb, cursor, tok_list, wt_list);

    if (big) {
        const int n8w = (int)(WELEM / 8);
        hipLaunchKernelGGL(cvt_bf16_kernel, dim3(2048), dim3(256), 0, stream, w1, w1bb, n8w);
        hipLaunchKernelGGL(cvt_bf16_kernel, dim3(2048), dim3(256), 0, stream, w3, w3bb, n8w);
        hipLaunchKernelGGL(cvt_bf16_kernel, dim3(256),  dim3(256), 0, stream, xn2, xn2b, T_ * HID_ / 8);
        hipLaunchKernelGGL(moe_gemm13_v2, dim3(INTER_ / 128, 16, E_), dim3(256), 0, stream,
                           xn2b, w1bb, w3bb, tok_list, ebase, counts, h13b);
        hipLaunchKernelGGL(cvt_bf16_kernel, dim3(2048), dim3(256), 0, stream, w2, w2bb, n8w);
        hipLaunchKernelGGL(copy4_kernel, dim3((T_ * HID_ / 4 + 255) / 256), dim3(256), 0, stream, h2, out, T_ * HID_ / 4);
        hipLaunchKernelGGL(moe_gemm2_v2, dim3(HID_ / 128, 16, E_), dim3(256), 0, stream,
                           (const short*)h13b, w2bb, tok_list, wt_list, ebase, counts, out);
    } else {
        hipLaunchKernelGGL(moe_gemm13_mfma, dim3(INTER_ / 128, 16, E_), dim3(256), 0, stream,
                           xn2, w1, w3, tok_list, ebase, counts, h13b);
        hipLaunchKernelGGL(copy4_kernel, dim3((T_ * HID_ / 4 + 255) / 256), dim3(256), 0, stream, h2, out, T_ * HID_ / 4);
        hipLaunchKernelGGL(moe_gemm2_mfma, dim3(HID_ / 128, 16, E_), dim3(256), 0, stream,
                           h13b, w2, tok_list, wt_list, ebase, counts, out);
    }
}